// Round 7
// baseline (347.123 us; speedup 1.0000x reference)
//
#include <hip/hip_runtime.h>

typedef _Float16 f16;
typedef _Float16 f16x8 __attribute__((ext_vector_type(8)));
typedef _Float16 f16x4 __attribute__((ext_vector_type(4)));
typedef float f32x4 __attribute__((ext_vector_type(4)));

__device__ __forceinline__ void gload16(const void* g, void* l) {
  __builtin_amdgcn_global_load_lds(
      (const __attribute__((address_space(1))) void*)g,
      (__attribute__((address_space(3))) void*)l, 16, 0, 0);
}

#define SCHED_FENCE __builtin_amdgcn_sched_barrier(0)
#define RAW_BARRIER do { SCHED_FENCE; __builtin_amdgcn_s_barrier(); SCHED_FENCE; } while (0)
#define WAIT_VM_0    do { asm volatile("s_waitcnt vmcnt(0)"     ::: "memory"); SCHED_FENCE; } while (0)
#define WAIT_VM_4    do { asm volatile("s_waitcnt vmcnt(4)"     ::: "memory"); SCHED_FENCE; } while (0)
#define WAIT_VM_8    do { asm volatile("s_waitcnt vmcnt(8)"     ::: "memory"); SCHED_FENCE; } while (0)
#define WAIT_LGKM_0  do { asm volatile("s_waitcnt lgkmcnt(0)"   ::: "memory"); SCHED_FENCE; } while (0)
#define WAIT_LGKM_11 do { asm volatile("s_waitcnt lgkmcnt(11)"  ::: "memory"); SCHED_FENCE; } while (0)

// ============ qkv GEMM: 256x192 tile, BK=32, 4-deep LDS pipeline, fused tile-norms =========
// C^T = (A(8192,1024) * B(3072,1024)^T + bias)^T written as qkvT (4,3072,2048).
// Grid 512 = 2 EXACT rounds at 1 block/CU (fixes the 384-block 75% round ceiling).
// 512 thr = 8 waves (2M x 4N), per-wave 128x48 = 8x3 frags. LDS 4 bufs x (A 16KB + B 12KB).
// B staging: 768 granules over 1024 slots -> top 256 slots duplicate granules 512-767
// (identical src->identical dest: idempotent) so every thread issues 4 loads/tile and the
// counted vmcnt gates stay wave-uniform. Fused epilogue: 2x2 tile-norms^2 of q,k from f32
// acc (pre-f16-rounding: closer to reference than the old separate f16-based pass).
__global__ __launch_bounds__(512, 2)
void gemm256_qkv(const f16* __restrict__ A, const f16* __restrict__ B,
                 f16* __restrict__ CT, const float* __restrict__ bias,
                 float* __restrict__ nq, float* __restrict__ nk)
{
  __shared__ f16 lds[4 * 14336];
  const int s = blockIdx.x;                       // 512, XCD-chunked swizzle
  const int tile = (s & 7) * 64 + (s >> 3);
  const int brow = (tile >> 4) << 8;              // 32 M-tiles of 256
  const int bcol = (tile & 15) * 192;             // 16 N-tiles of 192
  const int NT = 32;                              // K=1024 / 32
  const int tid = threadIdx.x;
  const int lane = tid & 63;
  const int wid = tid >> 6;
  const int wr = wid >> 2;
  const int wc = wid & 3;
  const int fr = lane & 15;
  const int kq = lane >> 4;

  const f16* pA[2]; const f16* pB[2]; int pdA[2], pdB[2];
#pragma unroll
  for (int i = 0; i < 2; i++) {
    const int p = wid * 128 + i * 64 + lane;                 // A slots 0..1023
    const int rr = ((p >> 6) << 4) | ((p >> 2) & 15);
    const int c4 = (p & 3) ^ ((p >> 3) & 3);
    pA[i] = A + (long)(brow + rr) * 1024 + c4 * 8;
    pdA[i] = p * 8;
    const int g = (p >= 768) ? p - 256 : p;                  // B granules 0..767 (dup tail)
    const int rb = ((g >> 6) << 4) | ((g >> 2) & 15);
    const int cb = (g & 3) ^ ((g >> 3) & 3);
    pB[i] = B + (long)(bcol + rb) * 1024 + cb * 8;
    pdB[i] = 8192 + g * 8;
  }

  auto STAGE = [&](int t) {
    f16* base = lds + (t & 3) * 14336;
    const int off = t * 32;
#pragma unroll
    for (int i = 0; i < 2; i++) {
      gload16(pA[i] + off, base + pdA[i]);
      gload16(pB[i] + off, base + pdB[i]);
    }
  };

  const int aoff0 = fr * 4 + (kq ^ ((fr >> 1) & 3));
  f32x4 acc[8][3] = {};
  f16x8 avA[8], bvA[3], avB[8], bvB[3];

  STAGE(0); STAGE(1); STAGE(2);
  WAIT_VM_4;                       // tiles 0,1 landed
  RAW_BARRIER;
#pragma unroll
  for (int m = 0; m < 8; m++)
    avA[m] = *(const f16x8*)(lds + ((wr * 8 + m) * 64 + aoff0) * 8);
#pragma unroll
  for (int n = 0; n < 3; n++)
    bvA[n] = *(const f16x8*)(lds + 8192 + ((wc * 3 + n) * 64 + aoff0) * 8);

#define GEMM_ITER(T, AVC, BVC, AVN, BVN)                                        \
  do {                                                                          \
    if ((T) + 3 < NT) STAGE((T) + 3);                                           \
    if ((T) + 1 < NT) {                                                         \
      const f16* nb_ = lds + (((T) + 1) & 3) * 14336;                           \
      _Pragma("unroll")                                                         \
      for (int m = 0; m < 8; m++)                                               \
        AVN[m] = *(const f16x8*)(nb_ + ((wr * 8 + m) * 64 + aoff0) * 8);        \
      _Pragma("unroll")                                                         \
      for (int n = 0; n < 3; n++)                                               \
        BVN[n] = *(const f16x8*)(nb_ + 8192 + ((wc * 3 + n) * 64 + aoff0) * 8); \
      WAIT_LGKM_11;                                                             \
    } else {                                                                    \
      WAIT_LGKM_0;                                                              \
    }                                                                           \
    __builtin_amdgcn_s_setprio(1);                                              \
    _Pragma("unroll")                                                           \
    for (int m = 0; m < 8; m++)                                                 \
      _Pragma("unroll")                                                         \
      for (int n = 0; n < 3; n++)                                               \
        acc[m][n] = __builtin_amdgcn_mfma_f32_16x16x32_f16(AVC[m], BVC[n],      \
                                                           acc[m][n], 0, 0, 0); \
    __builtin_amdgcn_s_setprio(0);                                              \
    if ((T) + 3 < NT)      { WAIT_VM_4; }                                       \
    else if ((T) + 2 < NT) { WAIT_VM_0; }                                       \
    RAW_BARRIER;                                                                \
  } while (0)

#pragma unroll 1
  for (int t = 0; t < NT; t += 2) {
    GEMM_ITER(t,     avA, bvA, avB, bvB);
    GEMM_ITER(t + 1, avB, bvB, avA, bvA);
  }
#undef GEMM_ITER

#pragma unroll
  for (int m = 0; m < 8; m++) {
    const int row0 = brow + wr * 128 + m * 16 + kq * 4;      // global s-row 0..8191
    const int bI = row0 >> 11, srow = row0 & 2047;
#pragma unroll
    for (int n = 0; n < 3; n++) {
      const int col = bcol + wc * 48 + n * 16 + fr;          // 0..3071
      const float bb = bias[col];
      const float v0 = acc[m][n][0] + bb, v1 = acc[m][n][1] + bb;
      const float v2 = acc[m][n][2] + bb, v3 = acc[m][n][3] + bb;
      f16x4 w = {(f16)v0, (f16)v1, (f16)v2, (f16)v3};
      *(f16x4*)&CT[((long)bI * 3072 + col) * 2048 + srow] = w;   // C^T: 4 contiguous s
      const int tcol = bcol + wc * 48 + n * 16;              // frag col base (uniform)
      if (tcol < 2048) {                                     // q,k only
        float h0 = v0 * v0 + v1 * v1;
        float h1 = v2 * v2 + v3 * v3;
        h0 += __shfl_xor(h0, 1, 64);                         // combine col pair (fr^1)
        h1 += __shfl_xor(h1, 1, 64);
        if (!(lane & 1)) {
          const int tau = tcol >> 10;
          float* dst = (tau ? nk : nq)
                     + ((long)bI * 1024 + (srow >> 1)) * 512 + ((col & 1023) >> 1);
          dst[0]   = h0;                                     // s2
          dst[512] = h1;                                     // s2+1
        }
      }
    }
  }
}

// ================= 128x128 GEMM, 4-buffer stage-lead-3 pipeline (R6-verified) =============
template<typename OutT, bool BIAS, bool TRANSC>
__device__ __forceinline__ void gemm_body(
    const f16* __restrict__ A, const f16* __restrict__ B,
    OutT* __restrict__ C, const float* __restrict__ bias,
    int K, int lda, int ldb, int ldc, float alpha, f16* lds, int brow, int bcol)
{
  const int NT = K >> 5;
  const int tid = threadIdx.x;
  const int lane = tid & 63;
  const int wid = tid >> 6;
  const int wr = (wid >> 1) << 6;
  const int wc = (wid & 1) << 6;
  const int fr = lane & 15;
  const int kq = lane >> 4;
  const int kqsw = kq ^ ((fr >> 1) & 3);

  const int srow = tid >> 2;
  const int skq  = (tid & 3) ^ ((tid >> 3) & 3);
  const f16* gA0 = A + (long)(brow + srow) * lda + skq * 8;
  const f16* gA1 = A + (long)(brow + 64 + srow) * lda + skq * 8;
  const f16* gB0 = B + (long)(bcol + srow) * ldb + skq * 8;
  const f16* gB1 = B + (long)(bcol + 64 + srow) * ldb + skq * 8;
  const int dA0 = tid * 8, dA1 = 2048 + tid * 8;
  const int dB0 = 4096 + tid * 8, dB1 = 6144 + tid * 8;

  auto STAGE = [&](int t) {
    f16* base = lds + (t & 3) * 8192;
    const int off = t * 32;
    gload16(gA0 + off, base + dA0);
    gload16(gA1 + off, base + dA1);
    gload16(gB0 + off, base + dB0);
    gload16(gB1 + off, base + dB1);
  };

  f32x4 acc[4][4] = {};

  STAGE(0); STAGE(1); STAGE(2);
  WAIT_VM_8;
  RAW_BARRIER;

#pragma unroll 1
  for (int t = 0; t < NT; ++t) {
    if (t + 3 < NT) STAGE(t + 3);
    SCHED_FENCE;
    const f16* base = lds + (t & 3) * 8192;
    f16x8 av[4], bv[4];
#pragma unroll
    for (int m = 0; m < 4; m++)
      av[m] = *(const f16x8*)(base + (wr + m * 16 + fr) * 32 + kqsw * 8);
#pragma unroll
    for (int n = 0; n < 4; n++)
      bv[n] = *(const f16x8*)(base + 4096 + (wc + n * 16 + fr) * 32 + kqsw * 8);
    __builtin_amdgcn_s_setprio(1);
#pragma unroll
    for (int m = 0; m < 4; m++)
#pragma unroll
      for (int n = 0; n < 4; n++)
        acc[m][n] = __builtin_amdgcn_mfma_f32_16x16x32_f16(av[m], bv[n], acc[m][n], 0, 0, 0);
    __builtin_amdgcn_s_setprio(0);
    if (t + 1 < NT) {
      WAIT_LGKM_0;
      if (t + 3 < NT)      { WAIT_VM_8; }
      else if (t + 2 < NT) { WAIT_VM_4; }
      else                 { WAIT_VM_0; }
      RAW_BARRIER;
    }
  }

#pragma unroll
  for (int m = 0; m < 4; m++)
#pragma unroll
    for (int n = 0; n < 4; n++) {
      const int row0 = brow + wr + m * 16 + kq * 4;
      const int col  = bcol + wc + n * 16 + fr;
      if constexpr (TRANSC) {
        f16x4 v;
#pragma unroll
        for (int i = 0; i < 4; i++) v[i] = (f16)(acc[m][n][i] * alpha);
        *(f16x4*)&C[(long)col * ldc + row0] = v;
      } else {
        float bb = 0.f;
        if constexpr (BIAS) bb = bias[col];
#pragma unroll
        for (int i = 0; i < 4; i++)
          C[(long)(row0 + i) * ldc + col] = (OutT)(acc[m][n][i] * alpha + bb);
      }
    }
}

template<typename OutT, bool BIAS, bool TRANSC>
__global__ __launch_bounds__(256)
void gemm_bt(const f16* __restrict__ A, const f16* __restrict__ B,
             OutT* __restrict__ C, const float* __restrict__ bias,
             int K, int lda, int ldb, int ldc,
             long sA, long sB, long sC, float alpha)
{
  __shared__ f16 lds[32768];
  const int bz = blockIdx.z;
  gemm_body<OutT, BIAS, TRANSC>(A + bz * sA, B + bz * sB, C + bz * sC, bias,
                                K, lda, ldb, ldc, alpha, lds,
                                blockIdx.y << 7, blockIdx.x << 7);
}

// merged stage-1: 3 products x 4 batches x 64 tiles of 128^2 = 768 blocks (>=3 blocks/CU ->
// no round quantization). XCD-chunked swizzle (768%8==0).
// p0: A1 = PqTm x PkTm^T /32 ; p1: B2 = vT x xT^T /32 (vT = qkvT v-slice) ; p2: Zt = xT x WOT^T /32
__global__ __launch_bounds__(256)
void gemm3_128(const f16* __restrict__ PqTm, const f16* __restrict__ PkTm, f16* __restrict__ A1,
               const f16* __restrict__ qkvT, const f16* __restrict__ xT, f16* __restrict__ B2,
               const f16* __restrict__ WOT, f16* __restrict__ Zt, float alpha)
{
  __shared__ f16 lds[32768];
  const int s = blockIdx.x;
  const int tile = (s & 7) * 96 + (s >> 3);
  const int z = tile >> 6, rem = tile & 63;
  const int p = z >> 2, b = z & 3;
  const f16 *A, *B; f16* C;
  if (p == 0)      { A = PqTm + (long)b * 1024 * 2048; B = PkTm + (long)b * 1024 * 2048;
                     C = A1 + (long)b * 1024 * 1024; }
  else if (p == 1) { A = qkvT + (long)b * 3072 * 2048 + 2048L * 2048; B = xT + (long)b * 1024 * 2048;
                     C = B2 + (long)b * 1024 * 1024; }
  else             { A = xT + (long)b * 1024 * 2048; B = WOT + (long)b * 1024 * 2048;
                     C = Zt + (long)b * 1024 * 1024; }
  gemm_body<f16, false, false>(A, B, C, nullptr, 2048, 2048, 2048, 1024, alpha, lds,
                               (rem >> 3) << 7, (rem & 7) << 7);
}

// ---------------- f32 -> f16 convert (vectorized x4)
__global__ __launch_bounds__(256)
void cvt_f32_f16(const float* __restrict__ in, f16* __restrict__ out, long n4) {
  long i = (long)blockIdx.x * 256 + threadIdx.x;
  if (i >= n4) return;
  float4 v = ((const float4*)in)[i];
  f16x4 o = {(f16)v.x, (f16)v.y, (f16)v.z, (f16)v.w};
  ((f16x4*)out)[i] = o;
}

// ---------------- fused x: f32 -> (xh f16, xT f16 transposed) in one pass
__global__ __launch_bounds__(256)
void cvtT_x(const float* __restrict__ x, f16* __restrict__ xh, f16* __restrict__ xT) {
  __shared__ f16 t[32][33];
  const int b = blockIdx.z;
  const int s0 = blockIdx.x * 32, d0 = blockIdx.y * 32;
  const int tx = threadIdx.x, ty = threadIdx.y;  // (32,8)
#pragma unroll
  for (int j = 0; j < 32; j += 8) {
    const long idx = ((long)b * 2048 + s0 + ty + j) * 1024 + d0 + tx;
    f16 h = (f16)x[idx];
    xh[idx] = h;
    t[ty + j][tx] = h;
  }
  __syncthreads();
#pragma unroll
  for (int j = 0; j < 32; j += 8)
    xT[((long)b * 1024 + d0 + ty + j) * 2048 + s0 + tx] = t[tx][ty + j];
}

// ---------------- WO row norms^2 (exact f32): one wave per row of (8192,1024)
__global__ __launch_bounds__(256)
void row_norms(const float* __restrict__ WO, float* __restrict__ wno) {
  const int wid = threadIdx.x >> 6, lane = threadIdx.x & 63;
  const long row = (long)blockIdx.x * 4 + wid;
  const float* p = WO + row * 1024;
  float s = 0.f;
#pragma unroll
  for (int j = 0; j < 4; j++) {
    float4 v = *(const float4*)(p + lane * 4 + j * 256);
    s += v.x*v.x + v.y*v.y + v.z*v.z + v.w*v.w;
  }
  for (int off = 32; off; off >>= 1) s += __shfl_down(s, off, 64);
  if (lane == 0) wno[row] = s;
}

// ---------------- radix-select of rank-r value: 2 passes x 4096 bins (bits 31:20, 19:8).
// thr keeps top-24 bits (low 8 zeroed): expected extra mask flips <5/problem vs the ~135
// fp16-rounding-induced flips -> negligible.
__global__ __launch_bounds__(256)
void select_init(unsigned* hist, unsigned* prefix, unsigned* rankrem) {
  int i = blockIdx.x * 256 + threadIdx.x;
  if (i < 12 * 4096) hist[i] = 0;
  if (i < 12) { prefix[i] = 0; rankrem[i] = (i < 8) ? 262144u : 1024u; }
}

__global__ __launch_bounds__(256)
void hist_pass(const float* __restrict__ nq, const float* __restrict__ nk,
               const float* __restrict__ wno, unsigned* __restrict__ hist,
               const unsigned* __restrict__ prefix,
               int shift, int nbins, unsigned himask) {
  __shared__ unsigned lh[4096];
  const int pid = blockIdx.y;
  for (int i = threadIdx.x; i < nbins; i += 256) lh[i] = 0;
  __syncthreads();
  const float* base; long N;
  if (pid < 4)      { base = nq  + (long)pid       * 524288; N = 524288; }
  else if (pid < 8) { base = nk  + (long)(pid - 4) * 524288; N = 524288; }
  else              { base = wno + (long)(pid - 8) * 2048;   N = 2048;  }
  const unsigned pref = prefix[pid];
  long chunk = (N + gridDim.x - 1) / gridDim.x;
  long s = (long)blockIdx.x * chunk;
  long e = s + chunk; if (e > N) e = N;
  for (long i = s + threadIdx.x; i < e; i += 256) {
    unsigned u = __float_as_uint(base[i]);
    if ((u & himask) == pref) atomicAdd(&lh[(u >> shift) & (nbins - 1)], 1u);
  }
  __syncthreads();
  for (int i = threadIdx.x; i < nbins; i += 256)
    if (lh[i]) atomicAdd(&hist[pid * 4096 + i], lh[i]);
}

__global__ __launch_bounds__(256)
void scan_pass(unsigned* __restrict__ hist, unsigned* __restrict__ prefix,
               unsigned* __restrict__ rankrem, float* __restrict__ thr,
               int shift, int nbins, int final_pass) {
  __shared__ unsigned buf[2][256];
  const int pid = blockIdx.x;
  const int tid = threadIdx.x;
  unsigned* h = hist + pid * 4096;
  const int per = nbins >> 8;  // 16
  const unsigned r = rankrem[pid];
  const unsigned oldpref = prefix[pid];
  unsigned local[16];
  unsigned s = 0;
#pragma unroll
  for (int j = 0; j < 16; j++) {
    if (j < per) {
      local[j] = h[tid * per + j];
      h[tid * per + j] = 0;
      s += local[j];
    }
  }
  buf[0][tid] = s;
  __syncthreads();
  int src = 0;
#pragma unroll
  for (int d = 1; d < 256; d <<= 1) {
    unsigned v = buf[src][tid];
    if (tid >= d) v += buf[src][tid - d];
    buf[src ^ 1][tid] = v;
    __syncthreads();
    src ^= 1;
  }
  const unsigned incl = buf[src][tid];
  const unsigned excl = incl - s;
  if (excl <= r && r < incl) {
    unsigned accu = excl;
#pragma unroll
    for (int j = 0; j < 16; j++) {
      if (j < per) {
        if (accu + local[j] > r) {
          rankrem[pid] = r - accu;
          unsigned np = oldpref | ((unsigned)(tid * per + j) << shift);
          prefix[pid] = np;
          if (final_pass) thr[pid] = __uint_as_float(np);
          break;
        }
        accu += local[j];
      }
    }
  }
}

// ---------------- masked q/k copy in d-major layout (qkvT slices -> PqTm/PkTm), no transpose
__global__ __launch_bounds__(256)
void mask_qkT(const f16* __restrict__ qkvT, const float* __restrict__ nq,
              const float* __restrict__ nk, const float* __restrict__ thr,
              f16* __restrict__ PqTm, f16* __restrict__ PkTm) {
  long i = (long)blockIdx.x * 256 + threadIdx.x;   // 2^20 per tau
  const int tau = blockIdx.y;
  const int s8 = (int)(i & 255);                   // 8-f16 group along s (coalesced)
  const int d  = (int)((i >> 8) & 1023);
  const int bI = (int)(i >> 18);
  f16x8 v = *(const f16x8*)(qkvT + ((long)bI * 3072 + tau * 1024 + d) * 2048 + s8 * 8);
  const float t = thr[tau * 4 + bI];
  const float* nb = (tau ? nk : nq) + (long)bI * 1024 * 512 + (d >> 1);
  const int s2b = s8 * 4;
#pragma unroll
  for (int j = 0; j < 4; j++) {
    if (nb[(long)(s2b + j) * 512] < t) { v[2*j] = (f16)0.f; v[2*j+1] = (f16)0.f; }
  }
  f16* dst = (tau ? PkTm : PqTm) + ((long)bI * 1024 + d) * 2048 + s8 * 8;
  *(f16x8*)dst = v;
}

// ---------------- fused WO row-mask + transpose + f32->f16: WO (b,2048,1024) -> WOT (b,1024,2048)
__global__ __launch_bounds__(256)
void wo_maskT(const float* __restrict__ WO, const float* __restrict__ wno,
              const float* __restrict__ thr, f16* __restrict__ WOT) {
  __shared__ f16 t[32][33];
  const int b = blockIdx.z;
  const int s0 = blockIdx.x * 32, d0 = blockIdx.y * 32;
  const int tx = threadIdx.x, ty = threadIdx.y;  // (32,8)
  const float tb = thr[8 + b];
#pragma unroll
  for (int j = 0; j < 32; j += 8) {
    const int s = s0 + ty + j;
    const float m = (wno[(long)b * 2048 + s] >= tb) ? 1.f : 0.f;
    t[ty + j][tx] = (f16)(WO[((long)b * 2048 + s) * 1024 + d0 + tx] * m);
  }
  __syncthreads();
#pragma unroll
  for (int j = 0; j < 32; j += 8)
    WOT[((long)b * 1024 + d0 + ty + j) * 2048 + s0 + tx] = t[tx][ty + j];
}

extern "C" void kernel_launch(void* const* d_in, const int* in_sizes, int n_in,
                              void* d_out, int out_size, void* d_ws, size_t ws_size,
                              hipStream_t stream) {
  const float* x    = (const float*)d_in[0];   // (4,2048,1024)
  const float* Wqkv = (const float*)d_in[1];   // (3072,1024)
  const float* bqkv = (const float*)d_in[2];   // (3072,)
  const float* WO   = (const float*)d_in[3];   // (4,1,2048,1024)
  float* out = (float*)d_out;                  // (4,2048,1024) f32

  char* w = (char*)d_ws;
  auto alloc = [&](size_t bytes) { char* p = w; w += (bytes + 255) & ~(size_t)255; return p; };
  f16*      xh      = (f16*)alloc(8192L * 1024 * 2);
  f16*      wh      = (f16*)alloc(3072L * 1024 * 2);
  f16*      xT      = (f16*)alloc(4L * 1024 * 2048 * 2);
  f16*      qkvT    = (f16*)alloc(4L * 3072 * 2048 * 2);
  float*    nq      = (float*)alloc(4L * 524288 * 4);
  float*    nk      = (float*)alloc(4L * 524288 * 4);
  float*    wno     = (float*)alloc(8192L * 4);
  unsigned* hist    = (unsigned*)alloc(12L * 4096 * 4);
  unsigned* prefix  = (unsigned*)alloc(256);
  unsigned* rankrem = (unsigned*)alloc(256);
  float*    thr     = (float*)alloc(256);
  f16*      WOT     = (f16*)alloc(4L * 1024 * 2048 * 2);
  f16*      PqTm    = (f16*)alloc(4L * 1024 * 2048 * 2);
  f16*      PkTm    = (f16*)alloc(4L * 1024 * 2048 * 2);
  f16*      Zt      = (f16*)alloc(4L * 1024 * 1024 * 2);
  f16*      A1      = (f16*)alloc(4L * 1024 * 1024 * 2);
  f16*      B2      = (f16*)alloc(4L * 1024 * 1024 * 2);
  f16*      M1      = (f16*)alloc(4L * 1024 * 1024 * 2);
  f16*      M2T     = (f16*)alloc(4L * 1024 * 1024 * 2);
  if ((size_t)(w - (char*)d_ws) > ws_size) return;  // workspace too small: fail visibly

  // 1. conversions
  cvtT_x<<<dim3(64, 32, 4), dim3(32, 8), 0, stream>>>(x, xh, xT);
  cvt_f32_f16<<<3072, 256, 0, stream>>>(Wqkv, wh, 3072L * 1024 / 4);
  // 2. qkv GEMM -> qkvT (C^T) with fused tile-norms; 512 blocks = 2 exact rounds
  gemm256_qkv<<<512, 512, 0, stream>>>(xh, wh, qkvT, bqkv, nq, nk);
  // 3. WO row norms
  row_norms<<<2048, 256, 0, stream>>>(WO, wno);
  // 4. medians via 2-pass radix select (bits 31:20, 19:8)
  select_init<<<192, 256, 0, stream>>>(hist, prefix, rankrem);
  hist_pass<<<dim3(32, 12), 256, 0, stream>>>(nq, nk, wno, hist, prefix, 20, 4096, 0u);
  scan_pass<<<12, 256, 0, stream>>>(hist, prefix, rankrem, thr, 20, 4096, 0);
  hist_pass<<<dim3(32, 12), 256, 0, stream>>>(nq, nk, wno, hist, prefix, 8, 4096, 0xFFF00000u);
  scan_pass<<<12, 256, 0, stream>>>(hist, prefix, rankrem, thr, 8, 4096, 1);
  // 5. masks: q,k elementwise in d-major; WO mask+transpose. (vT = qkvT v-slice, no copy)
  mask_qkT<<<dim3(4096, 2), 256, 0, stream>>>(qkvT, nq, nk, thr, PqTm, PkTm);
  wo_maskT<<<dim3(64, 32, 4), dim3(32, 8), 0, stream>>>(WO, wno, thr, WOT);
  // 6. chain: out = x.[Pq^T.Pk].[x^T.v].[WO_^T.x]/32
  gemm3_128<<<768, 256, 0, stream>>>(PqTm, PkTm, A1, qkvT, xT, B2, WOT, Zt, 0.03125f);
  // stage 2: M1 = A1.B2^T
  gemm_bt<f16, false, false><<<dim3(8, 8, 4), 256, 0, stream>>>(
      A1, B2, M1, nullptr, 1024, 1024, 1024, 1024,
      1024L * 1024, 1024L * 1024, 1024L * 1024, 1.f);
  // stage 3: M2T = (M1.Zt^T)^T / 4
  gemm_bt<f16, false, true><<<dim3(8, 8, 4), 256, 0, stream>>>(
      M1, Zt, M2T, nullptr, 1024, 1024, 1024, 1024,
      1024L * 1024, 1024L * 1024, 1024L * 1024, 0.25f);
  // stage 4: out = x.M2 * 4096  (total 4096/2^17 = 1/32)
  gemm_bt<float, false, false><<<dim3(8, 16, 4), 256, 0, stream>>>(
      xh, M2T, out, nullptr, 1024, 1024, 1024, 1024,
      2048L * 1024, 1024L * 1024, 2048L * 1024, 4096.f);
}

// Round 8
// 332.014 us; speedup vs baseline: 1.0455x; 1.0455x over previous
//
#include <hip/hip_runtime.h>

typedef _Float16 f16;
typedef _Float16 f16x8 __attribute__((ext_vector_type(8)));
typedef _Float16 f16x4 __attribute__((ext_vector_type(4)));
typedef float f32x4 __attribute__((ext_vector_type(4)));

__device__ __forceinline__ void gload16(const void* g, void* l) {
  __builtin_amdgcn_global_load_lds(
      (const __attribute__((address_space(1))) void*)g,
      (__attribute__((address_space(3))) void*)l, 16, 0, 0);
}

#define SCHED_FENCE __builtin_amdgcn_sched_barrier(0)
#define RAW_BARRIER do { SCHED_FENCE; __builtin_amdgcn_s_barrier(); SCHED_FENCE; } while (0)
#define WAIT_VM_0    do { asm volatile("s_waitcnt vmcnt(0)"     ::: "memory"); SCHED_FENCE; } while (0)
#define WAIT_VM_4    do { asm volatile("s_waitcnt vmcnt(4)"     ::: "memory"); SCHED_FENCE; } while (0)
#define WAIT_VM_8    do { asm volatile("s_waitcnt vmcnt(8)"     ::: "memory"); SCHED_FENCE; } while (0)
#define WAIT_LGKM_0  do { asm volatile("s_waitcnt lgkmcnt(0)"   ::: "memory"); SCHED_FENCE; } while (0)
#define WAIT_LGKM_11 do { asm volatile("s_waitcnt lgkmcnt(11)"  ::: "memory"); SCHED_FENCE; } while (0)

// ============ qkv GEMM (R7 body, unchanged = CONTROL for this round's phase-split A/B) =====
__global__ __launch_bounds__(512, 2)
void gemm256_qkv(const f16* __restrict__ A, const f16* __restrict__ B,
                 f16* __restrict__ CT, const float* __restrict__ bias,
                 float* __restrict__ nq, float* __restrict__ nk)
{
  __shared__ f16 lds[4 * 14336];
  const int s = blockIdx.x;
  const int tile = (s & 7) * 64 + (s >> 3);
  const int brow = (tile >> 4) << 8;
  const int bcol = (tile & 15) * 192;
  const int NT = 32;
  const int tid = threadIdx.x;
  const int lane = tid & 63;
  const int wid = tid >> 6;
  const int wr = wid >> 2;
  const int wc = wid & 3;
  const int fr = lane & 15;
  const int kq = lane >> 4;

  const f16* pA[2]; const f16* pB[2]; int pdA[2], pdB[2];
#pragma unroll
  for (int i = 0; i < 2; i++) {
    const int p = wid * 128 + i * 64 + lane;
    const int rr = ((p >> 6) << 4) | ((p >> 2) & 15);
    const int c4 = (p & 3) ^ ((p >> 3) & 3);
    pA[i] = A + (long)(brow + rr) * 1024 + c4 * 8;
    pdA[i] = p * 8;
    const int g = (p >= 768) ? p - 256 : p;
    const int rb = ((g >> 6) << 4) | ((g >> 2) & 15);
    const int cb = (g & 3) ^ ((g >> 3) & 3);
    pB[i] = B + (long)(bcol + rb) * 1024 + cb * 8;
    pdB[i] = 8192 + g * 8;
  }

  auto STAGE = [&](int t) {
    f16* base = lds + (t & 3) * 14336;
    const int off = t * 32;
#pragma unroll
    for (int i = 0; i < 2; i++) {
      gload16(pA[i] + off, base + pdA[i]);
      gload16(pB[i] + off, base + pdB[i]);
    }
  };

  const int aoff0 = fr * 4 + (kq ^ ((fr >> 1) & 3));
  f32x4 acc[8][3] = {};
  f16x8 avA[8], bvA[3], avB[8], bvB[3];

  STAGE(0); STAGE(1); STAGE(2);
  WAIT_VM_4;
  RAW_BARRIER;
#pragma unroll
  for (int m = 0; m < 8; m++)
    avA[m] = *(const f16x8*)(lds + ((wr * 8 + m) * 64 + aoff0) * 8);
#pragma unroll
  for (int n = 0; n < 3; n++)
    bvA[n] = *(const f16x8*)(lds + 8192 + ((wc * 3 + n) * 64 + aoff0) * 8);

#define GEMM_ITER(T, AVC, BVC, AVN, BVN)                                        \
  do {                                                                          \
    if ((T) + 3 < NT) STAGE((T) + 3);                                           \
    if ((T) + 1 < NT) {                                                         \
      const f16* nb_ = lds + (((T) + 1) & 3) * 14336;                           \
      _Pragma("unroll")                                                         \
      for (int m = 0; m < 8; m++)                                               \
        AVN[m] = *(const f16x8*)(nb_ + ((wr * 8 + m) * 64 + aoff0) * 8);        \
      _Pragma("unroll")                                                         \
      for (int n = 0; n < 3; n++)                                               \
        BVN[n] = *(const f16x8*)(nb_ + 8192 + ((wc * 3 + n) * 64 + aoff0) * 8); \
      WAIT_LGKM_11;                                                             \
    } else {                                                                    \
      WAIT_LGKM_0;                                                              \
    }                                                                           \
    __builtin_amdgcn_s_setprio(1);                                              \
    _Pragma("unroll")                                                           \
    for (int m = 0; m < 8; m++)                                                 \
      _Pragma("unroll")                                                         \
      for (int n = 0; n < 3; n++)                                               \
        acc[m][n] = __builtin_amdgcn_mfma_f32_16x16x32_f16(AVC[m], BVC[n],      \
                                                           acc[m][n], 0, 0, 0); \
    __builtin_amdgcn_s_setprio(0);                                              \
    if ((T) + 3 < NT)      { WAIT_VM_4; }                                       \
    else if ((T) + 2 < NT) { WAIT_VM_0; }                                       \
    RAW_BARRIER;                                                                \
  } while (0)

#pragma unroll 1
  for (int t = 0; t < NT; t += 2) {
    GEMM_ITER(t,     avA, bvA, avB, bvB);
    GEMM_ITER(t + 1, avB, bvB, avA, bvA);
  }
#undef GEMM_ITER

#pragma unroll
  for (int m = 0; m < 8; m++) {
    const int row0 = brow + wr * 128 + m * 16 + kq * 4;
    const int bI = row0 >> 11, srow = row0 & 2047;
#pragma unroll
    for (int n = 0; n < 3; n++) {
      const int col = bcol + wc * 48 + n * 16 + fr;
      const float bb = bias[col];
      const float v0 = acc[m][n][0] + bb, v1 = acc[m][n][1] + bb;
      const float v2 = acc[m][n][2] + bb, v3 = acc[m][n][3] + bb;
      f16x4 w = {(f16)v0, (f16)v1, (f16)v2, (f16)v3};
      *(f16x4*)&CT[((long)bI * 3072 + col) * 2048 + srow] = w;
      const int tcol = bcol + wc * 48 + n * 16;
      if (tcol < 2048) {
        float h0 = v0 * v0 + v1 * v1;
        float h1 = v2 * v2 + v3 * v3;
        h0 += __shfl_xor(h0, 1, 64);
        h1 += __shfl_xor(h1, 1, 64);
        if (!(lane & 1)) {
          const int tau = tcol >> 10;
          float* dst = (tau ? nk : nq)
                     + ((long)bI * 1024 + (srow >> 1)) * 512 + ((col & 1023) >> 1);
          dst[0]   = h0;
          dst[512] = h1;
        }
      }
    }
  }
}

// ============ 128x128 GEMM: 4-buffer stage-lead-3 + NEW 2-phase split per K-tile ===========
// EXPERIMENT (T3-lite): per K-tile, two phases each with {stage 2 gloads | ds_reads |
// barrier | lgkm0 | setprio(1) | 8 MFMA | setprio(0) | [vm gate] | barrier} -> creates
// intra-phase wave role-diversity (one wave reads LDS while SIMD-mate runs MFMA).
// Staging layout, lead-3, and vmcnt counts identical to the race-verified R6 structure.
template<typename OutT, bool BIAS, bool TRANSC>
__device__ __forceinline__ void gemm_body(
    const f16* __restrict__ A, const f16* __restrict__ B,
    OutT* __restrict__ C, const float* __restrict__ bias,
    int K, int lda, int ldb, int ldc, float alpha, f16* lds, int brow, int bcol)
{
  const int NT = K >> 5;
  const int tid = threadIdx.x;
  const int lane = tid & 63;
  const int wid = tid >> 6;
  const int wr = (wid >> 1) << 6;
  const int wc = (wid & 1) << 6;
  const int fr = lane & 15;
  const int kq = lane >> 4;
  const int kqsw = kq ^ ((fr >> 1) & 3);

  const int srow = tid >> 2;
  const int skq  = (tid & 3) ^ ((tid >> 3) & 3);
  const f16* gA0 = A + (long)(brow + srow) * lda + skq * 8;
  const f16* gA1 = A + (long)(brow + 64 + srow) * lda + skq * 8;
  const f16* gB0 = B + (long)(bcol + srow) * ldb + skq * 8;
  const f16* gB1 = B + (long)(bcol + 64 + srow) * ldb + skq * 8;
  const int dA0 = tid * 8, dA1 = 2048 + tid * 8;
  const int dB0 = 4096 + tid * 8, dB1 = 6144 + tid * 8;

  f32x4 acc[4][4] = {};

  // prologue: full stages of tiles 0,1,2 (4 loads each)
  {
    f16* b0 = lds;            gload16(gA0, b0 + dA0); gload16(gA1, b0 + dA1);
                              gload16(gB0, b0 + dB0); gload16(gB1, b0 + dB1);
    f16* b1 = lds + 8192;     gload16(gA0 + 32, b1 + dA0); gload16(gA1 + 32, b1 + dA1);
                              gload16(gB0 + 32, b1 + dB0); gload16(gB1 + 32, b1 + dB1);
    f16* b2 = lds + 16384;    gload16(gA0 + 64, b2 + dA0); gload16(gA1 + 64, b2 + dA1);
                              gload16(gB0 + 64, b2 + dB0); gload16(gB1 + 64, b2 + dB1);
  }
  WAIT_VM_8;
  RAW_BARRIER;

#pragma unroll 1
  for (int t = 0; t < NT; ++t) {
    const f16* base = lds + (t & 3) * 8192;
    f16* sb = lds + ((t + 3) & 3) * 8192;
    const int soff = (t + 3) * 32;
    f16x8 av[4], bv[4];
    // ---- phase 0: stage A(t+3) | read A-frags + B n0,n1 | 8 MFMA (n0-1)
    if (t + 3 < NT) { gload16(gA0 + soff, sb + dA0); gload16(gA1 + soff, sb + dA1); }
    SCHED_FENCE;
#pragma unroll
    for (int m = 0; m < 4; m++)
      av[m] = *(const f16x8*)(base + (wr + m * 16 + fr) * 32 + kqsw * 8);
#pragma unroll
    for (int n = 0; n < 2; n++)
      bv[n] = *(const f16x8*)(base + 4096 + (wc + n * 16 + fr) * 32 + kqsw * 8);
    RAW_BARRIER;
    WAIT_LGKM_0;
    __builtin_amdgcn_s_setprio(1);
#pragma unroll
    for (int m = 0; m < 4; m++)
#pragma unroll
      for (int n = 0; n < 2; n++)
        acc[m][n] = __builtin_amdgcn_mfma_f32_16x16x32_f16(av[m], bv[n], acc[m][n], 0, 0, 0);
    __builtin_amdgcn_s_setprio(0);
    RAW_BARRIER;
    // ---- phase 1: stage B(t+3) | read B n2,n3 | 8 MFMA (n2-3) | vm gate
    if (t + 3 < NT) { gload16(gB0 + soff, sb + dB0); gload16(gB1 + soff, sb + dB1); }
    SCHED_FENCE;
#pragma unroll
    for (int n = 2; n < 4; n++)
      bv[n] = *(const f16x8*)(base + 4096 + (wc + n * 16 + fr) * 32 + kqsw * 8);
    RAW_BARRIER;
    WAIT_LGKM_0;
    __builtin_amdgcn_s_setprio(1);
#pragma unroll
    for (int m = 0; m < 4; m++)
#pragma unroll
      for (int n = 2; n < 4; n++)
        acc[m][n] = __builtin_amdgcn_mfma_f32_16x16x32_f16(av[m], bv[n], acc[m][n], 0, 0, 0);
    __builtin_amdgcn_s_setprio(0);
    if (t + 1 < NT) {
      if (t + 3 < NT)      { WAIT_VM_8; }
      else if (t + 2 < NT) { WAIT_VM_4; }
      else                 { WAIT_VM_0; }
      RAW_BARRIER;
    }
  }

#pragma unroll
  for (int m = 0; m < 4; m++)
#pragma unroll
    for (int n = 0; n < 4; n++) {
      const int row0 = brow + wr + m * 16 + kq * 4;
      const int col  = bcol + wc + n * 16 + fr;
      if constexpr (TRANSC) {
        f16x4 v;
#pragma unroll
        for (int i = 0; i < 4; i++) v[i] = (f16)(acc[m][n][i] * alpha);
        *(f16x4*)&C[(long)col * ldc + row0] = v;
      } else {
        float bb = 0.f;
        if constexpr (BIAS) bb = bias[col];
#pragma unroll
        for (int i = 0; i < 4; i++)
          C[(long)(row0 + i) * ldc + col] = (OutT)(acc[m][n][i] * alpha + bb);
      }
    }
}

template<typename OutT, bool BIAS, bool TRANSC>
__global__ __launch_bounds__(256)
void gemm_bt(const f16* __restrict__ A, const f16* __restrict__ B,
             OutT* __restrict__ C, const float* __restrict__ bias,
             int K, int lda, int ldb, int ldc,
             long sA, long sB, long sC, float alpha)
{
  __shared__ f16 lds[32768];
  const int bz = blockIdx.z;
  gemm_body<OutT, BIAS, TRANSC>(A + bz * sA, B + bz * sB, C + bz * sC, bias,
                                K, lda, ldb, ldc, alpha, lds,
                                blockIdx.y << 7, blockIdx.x << 7);
}

// merged stage-1: 3 products x 4 batches x 64 tiles of 128^2 = 768 blocks, XCD swizzle
__global__ __launch_bounds__(256)
void gemm3_128(const f16* __restrict__ PqTm, const f16* __restrict__ PkTm, f16* __restrict__ A1,
               const f16* __restrict__ qkvT, const f16* __restrict__ xT, f16* __restrict__ B2,
               const f16* __restrict__ WOT, f16* __restrict__ Zt, float alpha)
{
  __shared__ f16 lds[32768];
  const int s = blockIdx.x;
  const int tile = (s & 7) * 96 + (s >> 3);
  const int z = tile >> 6, rem = tile & 63;
  const int p = z >> 2, b = z & 3;
  const f16 *A, *B; f16* C;
  if (p == 0)      { A = PqTm + (long)b * 1024 * 2048; B = PkTm + (long)b * 1024 * 2048;
                     C = A1 + (long)b * 1024 * 1024; }
  else if (p == 1) { A = qkvT + (long)b * 3072 * 2048 + 2048L * 2048; B = xT + (long)b * 1024 * 2048;
                     C = B2 + (long)b * 1024 * 1024; }
  else             { A = xT + (long)b * 1024 * 2048; B = WOT + (long)b * 1024 * 2048;
                     C = Zt + (long)b * 1024 * 1024; }
  gemm_body<f16, false, false>(A, B, C, nullptr, 2048, 2048, 2048, 1024, alpha, lds,
                               (rem >> 3) << 7, (rem & 7) << 7);
}

// ---------------- f32 -> f16 convert (vectorized x4)
__global__ __launch_bounds__(256)
void cvt_f32_f16(const float* __restrict__ in, f16* __restrict__ out, long n4) {
  long i = (long)blockIdx.x * 256 + threadIdx.x;
  if (i >= n4) return;
  float4 v = ((const float4*)in)[i];
  f16x4 o = {(f16)v.x, (f16)v.y, (f16)v.z, (f16)v.w};
  ((f16x4*)out)[i] = o;
}

// ---------------- fused x: f32 -> (xh f16, xT f16 transposed) in one pass
__global__ __launch_bounds__(256)
void cvtT_x(const float* __restrict__ x, f16* __restrict__ xh, f16* __restrict__ xT) {
  __shared__ f16 t[32][33];
  const int b = blockIdx.z;
  const int s0 = blockIdx.x * 32, d0 = blockIdx.y * 32;
  const int tx = threadIdx.x, ty = threadIdx.y;  // (32,8)
#pragma unroll
  for (int j = 0; j < 32; j += 8) {
    const long idx = ((long)b * 2048 + s0 + ty + j) * 1024 + d0 + tx;
    f16 h = (f16)x[idx];
    xh[idx] = h;
    t[ty + j][tx] = h;
  }
  __syncthreads();
#pragma unroll
  for (int j = 0; j < 32; j += 8)
    xT[((long)b * 1024 + d0 + ty + j) * 2048 + s0 + tx] = t[tx][ty + j];
}

// ---------------- WO row norms^2 (exact f32)
__global__ __launch_bounds__(256)
void row_norms(const float* __restrict__ WO, float* __restrict__ wno) {
  const int wid = threadIdx.x >> 6, lane = threadIdx.x & 63;
  const long row = (long)blockIdx.x * 4 + wid;
  const float* p = WO + row * 1024;
  float s = 0.f;
#pragma unroll
  for (int j = 0; j < 4; j++) {
    float4 v = *(const float4*)(p + lane * 4 + j * 256);
    s += v.x*v.x + v.y*v.y + v.z*v.z + v.w*v.w;
  }
  for (int off = 32; off; off >>= 1) s += __shfl_down(s, off, 64);
  if (lane == 0) wno[row] = s;
}

// ---------------- norms transpose: nq/nk [b][s2:1024][d2:512] -> nqT/nkT [b][d2:512][s2:1024]
__global__ __launch_bounds__(256)
void normsT(const float* __restrict__ nq, const float* __restrict__ nk,
            float* __restrict__ nqT, float* __restrict__ nkT) {
  __shared__ float t[32][33];
  const int z = blockIdx.z;                      // 0-3: nq batches, 4-7: nk
  const float* src = (z < 4 ? nq : nk) + (long)(z & 3) * 524288;
  float* dst = (z < 4 ? nqT : nkT) + (long)(z & 3) * 524288;
  const int s0 = blockIdx.x * 32, d0 = blockIdx.y * 32;   // grid (32, 16)
  const int tx = threadIdx.x, ty = threadIdx.y;  // (32,8)
#pragma unroll
  for (int j = 0; j < 32; j += 8)
    t[ty + j][tx] = src[(long)(s0 + ty + j) * 512 + d0 + tx];
  __syncthreads();
#pragma unroll
  for (int j = 0; j < 32; j += 8)
    dst[(long)(d0 + ty + j) * 1024 + s0 + tx] = t[tx][ty + j];
}

// ---------------- radix-select: 2 passes x 4096 bins (bits 31:20, 19:8)
__global__ __launch_bounds__(256)
void select_init(unsigned* hist, unsigned* prefix, unsigned* rankrem) {
  int i = blockIdx.x * 256 + threadIdx.x;
  if (i < 12 * 4096) hist[i] = 0;
  if (i < 12) { prefix[i] = 0; rankrem[i] = (i < 8) ? 262144u : 1024u; }
}

__global__ __launch_bounds__(256)
void hist_pass(const float* __restrict__ nq, const float* __restrict__ nk,
               const float* __restrict__ wno, unsigned* __restrict__ hist,
               const unsigned* __restrict__ prefix,
               int shift, int nbins, unsigned himask) {
  __shared__ unsigned lh[4096];
  const int pid = blockIdx.y;
  for (int i = threadIdx.x; i < nbins; i += 256) lh[i] = 0;
  __syncthreads();
  const float* base; long N;
  if (pid < 4)      { base = nq  + (long)pid       * 524288; N = 524288; }
  else if (pid < 8) { base = nk  + (long)(pid - 4) * 524288; N = 524288; }
  else              { base = wno + (long)(pid - 8) * 2048;   N = 2048;  }
  const unsigned pref = prefix[pid];
  long chunk = (N + gridDim.x - 1) / gridDim.x;
  long s = (long)blockIdx.x * chunk;
  long e = s + chunk; if (e > N) e = N;
  for (long i = s + threadIdx.x; i < e; i += 256) {
    unsigned u = __float_as_uint(base[i]);
    if ((u & himask) == pref) atomicAdd(&lh[(u >> shift) & (nbins - 1)], 1u);
  }
  __syncthreads();
  for (int i = threadIdx.x; i < nbins; i += 256)
    if (lh[i]) atomicAdd(&hist[pid * 4096 + i], lh[i]);
}

__global__ __launch_bounds__(256)
void scan_pass(unsigned* __restrict__ hist, unsigned* __restrict__ prefix,
               unsigned* __restrict__ rankrem, float* __restrict__ thr,
               int shift, int nbins, int final_pass) {
  __shared__ unsigned buf[2][256];
  const int pid = blockIdx.x;
  const int tid = threadIdx.x;
  unsigned* h = hist + pid * 4096;
  const int per = nbins >> 8;
  const unsigned r = rankrem[pid];
  const unsigned oldpref = prefix[pid];
  unsigned local[16];
  unsigned s = 0;
#pragma unroll
  for (int j = 0; j < 16; j++) {
    if (j < per) {
      local[j] = h[tid * per + j];
      h[tid * per + j] = 0;
      s += local[j];
    }
  }
  buf[0][tid] = s;
  __syncthreads();
  int src = 0;
#pragma unroll
  for (int d = 1; d < 256; d <<= 1) {
    unsigned v = buf[src][tid];
    if (tid >= d) v += buf[src][tid - d];
    buf[src ^ 1][tid] = v;
    __syncthreads();
    src ^= 1;
  }
  const unsigned incl = buf[src][tid];
  const unsigned excl = incl - s;
  if (excl <= r && r < incl) {
    unsigned accu = excl;
#pragma unroll
    for (int j = 0; j < 16; j++) {
      if (j < per) {
        if (accu + local[j] > r) {
          rankrem[pid] = r - accu;
          unsigned np = oldpref | ((unsigned)(tid * per + j) << shift);
          prefix[pid] = np;
          if (final_pass) thr[pid] = __uint_as_float(np);
          break;
        }
        accu += local[j];
      }
    }
  }
}

// ---------------- masked q/k copy, d-major, COALESCED norm reads via transposed norms
// one block per (bI, tau, d-row): 256 thr x 8 f16 = 2048 s; norms nqT[d2] row 16B/thread
__global__ __launch_bounds__(256)
void mask_qkT(const f16* __restrict__ qkvT, const float* __restrict__ nqT,
              const float* __restrict__ nkT, const float* __restrict__ thr,
              f16* __restrict__ PqTm, f16* __restrict__ PkTm) {
  const int d  = blockIdx.x & 1023;
  const int tau = (blockIdx.x >> 10) & 1;
  const int bI = blockIdx.x >> 11;
  const int s8 = threadIdx.x;
  f16x8 v = *(const f16x8*)(qkvT + ((long)bI * 3072 + tau * 1024 + d) * 2048 + s8 * 8);
  const float t = thr[tau * 4 + bI];
  const float4 nv = *(const float4*)((tau ? nkT : nqT)
                     + ((long)bI * 512 + (d >> 1)) * 1024 + s8 * 4);
  if (nv.x < t) { v[0] = (f16)0.f; v[1] = (f16)0.f; }
  if (nv.y < t) { v[2] = (f16)0.f; v[3] = (f16)0.f; }
  if (nv.z < t) { v[4] = (f16)0.f; v[5] = (f16)0.f; }
  if (nv.w < t) { v[6] = (f16)0.f; v[7] = (f16)0.f; }
  f16* dst = (tau ? PkTm : PqTm) + ((long)bI * 1024 + d) * 2048 + s8 * 8;
  *(f16x8*)dst = v;
}

// ---------------- fused WO row-mask + transpose + f32->f16
__global__ __launch_bounds__(256)
void wo_maskT(const float* __restrict__ WO, const float* __restrict__ wno,
              const float* __restrict__ thr, f16* __restrict__ WOT) {
  __shared__ f16 t[32][33];
  const int b = blockIdx.z;
  const int s0 = blockIdx.x * 32, d0 = blockIdx.y * 32;
  const int tx = threadIdx.x, ty = threadIdx.y;
  const float tb = thr[8 + b];
#pragma unroll
  for (int j = 0; j < 32; j += 8) {
    const int s = s0 + ty + j;
    const float m = (wno[(long)b * 2048 + s] >= tb) ? 1.f : 0.f;
    t[ty + j][tx] = (f16)(WO[((long)b * 2048 + s) * 1024 + d0 + tx] * m);
  }
  __syncthreads();
#pragma unroll
  for (int j = 0; j < 32; j += 8)
    WOT[((long)b * 1024 + d0 + ty + j) * 2048 + s0 + tx] = t[tx][ty + j];
}

extern "C" void kernel_launch(void* const* d_in, const int* in_sizes, int n_in,
                              void* d_out, int out_size, void* d_ws, size_t ws_size,
                              hipStream_t stream) {
  const float* x    = (const float*)d_in[0];
  const float* Wqkv = (const float*)d_in[1];
  const float* bqkv = (const float*)d_in[2];
  const float* WO   = (const float*)d_in[3];
  float* out = (float*)d_out;

  char* w = (char*)d_ws;
  auto alloc = [&](size_t bytes) { char* p = w; w += (bytes + 255) & ~(size_t)255; return p; };
  f16*      xh      = (f16*)alloc(8192L * 1024 * 2);
  f16*      wh      = (f16*)alloc(3072L * 1024 * 2);
  f16*      xT      = (f16*)alloc(4L * 1024 * 2048 * 2);
  f16*      qkvT    = (f16*)alloc(4L * 3072 * 2048 * 2);
  float*    nq      = (float*)alloc(4L * 524288 * 4);
  float*    nk      = (float*)alloc(4L * 524288 * 4);
  float*    nqT     = (float*)alloc(4L * 524288 * 4);
  float*    nkT     = (float*)alloc(4L * 524288 * 4);
  float*    wno     = (float*)alloc(8192L * 4);
  unsigned* hist    = (unsigned*)alloc(12L * 4096 * 4);
  unsigned* prefix  = (unsigned*)alloc(256);
  unsigned* rankrem = (unsigned*)alloc(256);
  float*    thr     = (float*)alloc(256);
  f16*      WOT     = (f16*)alloc(4L * 1024 * 2048 * 2);
  f16*      PqTm    = (f16*)alloc(4L * 1024 * 2048 * 2);
  f16*      PkTm    = (f16*)alloc(4L * 1024 * 2048 * 2);
  f16*      Zt      = (f16*)alloc(4L * 1024 * 1024 * 2);
  f16*      A1      = (f16*)alloc(4L * 1024 * 1024 * 2);
  f16*      B2      = (f16*)alloc(4L * 1024 * 1024 * 2);
  f16*      M1      = (f16*)alloc(4L * 1024 * 1024 * 2);
  f16*      M2T     = (f16*)alloc(4L * 1024 * 1024 * 2);
  if ((size_t)(w - (char*)d_ws) > ws_size) return;

  // 1. conversions
  cvtT_x<<<dim3(64, 32, 4), dim3(32, 8), 0, stream>>>(x, xh, xT);
  cvt_f32_f16<<<3072, 256, 0, stream>>>(Wqkv, wh, 3072L * 1024 / 4);
  // 2. qkv GEMM -> qkvT with fused f32-acc tile-norms
  gemm256_qkv<<<512, 512, 0, stream>>>(xh, wh, qkvT, bqkv, nq, nk);
  // 3. WO row norms + norm transpose (for coalesced mask reads)
  row_norms<<<2048, 256, 0, stream>>>(WO, wno);
  normsT<<<dim3(32, 16, 8), dim3(32, 8), 0, stream>>>(nq, nk, nqT, nkT);
  // 4. medians via 2-pass radix select
  select_init<<<192, 256, 0, stream>>>(hist, prefix, rankrem);
  hist_pass<<<dim3(32, 12), 256, 0, stream>>>(nq, nk, wno, hist, prefix, 20, 4096, 0u);
  scan_pass<<<12, 256, 0, stream>>>(hist, prefix, rankrem, thr, 20, 4096, 0);
  hist_pass<<<dim3(32, 12), 256, 0, stream>>>(nq, nk, wno, hist, prefix, 8, 4096, 0xFFF00000u);
  scan_pass<<<12, 256, 0, stream>>>(hist, prefix, rankrem, thr, 8, 4096, 1);
  // 5. masks
  mask_qkT<<<8192, 256, 0, stream>>>(qkvT, nqT, nkT, thr, PqTm, PkTm);
  wo_maskT<<<dim3(64, 32, 4), dim3(32, 8), 0, stream>>>(WO, wno, thr, WOT);
  // 6. chain
  gemm3_128<<<768, 256, 0, stream>>>(PqTm, PkTm, A1, qkvT, xT, B2, WOT, Zt, 0.03125f);
  gemm_bt<f16, false, false><<<dim3(8, 8, 4), 256, 0, stream>>>(
      A1, B2, M1, nullptr, 1024, 1024, 1024, 1024,
      1024L * 1024, 1024L * 1024, 1024L * 1024, 1.f);
  gemm_bt<f16, false, true><<<dim3(8, 8, 4), 256, 0, stream>>>(
      M1, Zt, M2T, nullptr, 1024, 1024, 1024, 1024,
      1024L * 1024, 1024L * 1024, 1024L * 1024, 0.25f);
  gemm_bt<float, false, false><<<dim3(8, 16, 4), 256, 0, stream>>>(
      xh, M2T, out, nullptr, 1024, 1024, 1024, 1024,
      2048L * 1024, 1024L * 1024, 2048L * 1024, 4096.f);
}

// Round 9
// 326.067 us; speedup vs baseline: 1.0646x; 1.0182x over previous
//
#include <hip/hip_runtime.h>

typedef _Float16 f16;
typedef _Float16 f16x8 __attribute__((ext_vector_type(8)));
typedef _Float16 f16x4 __attribute__((ext_vector_type(4)));
typedef float f32x4 __attribute__((ext_vector_type(4)));

__device__ __forceinline__ void gload16(const void* g, void* l) {
  __builtin_amdgcn_global_load_lds(
      (const __attribute__((address_space(1))) void*)g,
      (__attribute__((address_space(3))) void*)l, 16, 0, 0);
}

#define SCHED_FENCE __builtin_amdgcn_sched_barrier(0)
#define RAW_BARRIER do { SCHED_FENCE; __builtin_amdgcn_s_barrier(); SCHED_FENCE; } while (0)
#define WAIT_VM_0    do { asm volatile("s_waitcnt vmcnt(0)"     ::: "memory"); SCHED_FENCE; } while (0)
#define WAIT_VM_4    do { asm volatile("s_waitcnt vmcnt(4)"     ::: "memory"); SCHED_FENCE; } while (0)
#define WAIT_VM_8    do { asm volatile("s_waitcnt vmcnt(8)"     ::: "memory"); SCHED_FENCE; } while (0)
#define WAIT_LGKM_0  do { asm volatile("s_waitcnt lgkmcnt(0)"   ::: "memory"); SCHED_FENCE; } while (0)

// ============ qkv GEMM: 256x192, BK=32, 4-deep staging + NEW per-K-tile 2-phase split ======
// T3 experiment in the CONFIRMED regime (8 waves / 512 thr; m232: 4-wave quadrant is null,
// 8-wave is +18-41%). Per K-tile, two phases each with the m201 signature:
// {stage 1 gload-pair | issue quadrant ds_reads | barrier | lgkmcnt(0) | setprio(1) |
//  12 MFMA | setprio(0) | [counted vm-gate] | barrier}.
// Phase 0: A m0-3 (4 b128) + B n0-2 (3 b128), MFMA m0-3 x n0-2.
// Phase 1: A m4-7 (4 b128, B retained in regs), MFMA m4-7 x n0-2.
// Staging/race ledger identical to the verified R7 control: buf[(t+3)&3] = buf[(t-1)&3],
// whose readers all retired (phase-1 lgkm0) before iter t-1's final barrier. vm gates:
// steady vm(8) = tile t+1 landed, t+2/t+3 in flight; drain 4 -> 0; never 0 mid-loop.
// Fused epilogue: C^T write + f32-acc 2x2 tile-norms (unchanged).
__global__ __launch_bounds__(512, 2)
void gemm256_qkv(const f16* __restrict__ A, const f16* __restrict__ B,
                 f16* __restrict__ CT, const float* __restrict__ bias,
                 float* __restrict__ nq, float* __restrict__ nk)
{
  __shared__ f16 lds[4 * 14336];
  const int s = blockIdx.x;                       // 512 blocks = 2 exact rounds
  const int tile = (s & 7) * 64 + (s >> 3);       // XCD-chunked swizzle (512%8==0)
  const int brow = (tile >> 4) << 8;
  const int bcol = (tile & 15) * 192;
  const int NT = 32;
  const int tid = threadIdx.x;
  const int lane = tid & 63;
  const int wid = tid >> 6;
  const int wr = wid >> 2;
  const int wc = wid & 3;
  const int fr = lane & 15;
  const int kq = lane >> 4;

  const f16* pA[2]; const f16* pB[2]; int pdA[2], pdB[2];
#pragma unroll
  for (int i = 0; i < 2; i++) {
    const int p = wid * 128 + i * 64 + lane;
    const int rr = ((p >> 6) << 4) | ((p >> 2) & 15);
    const int c4 = (p & 3) ^ ((p >> 3) & 3);
    pA[i] = A + (long)(brow + rr) * 1024 + c4 * 8;
    pdA[i] = p * 8;
    const int g = (p >= 768) ? p - 256 : p;       // B: 768 granules, idempotent dup tail
    const int rb = ((g >> 6) << 4) | ((g >> 2) & 15);
    const int cb = (g & 3) ^ ((g >> 3) & 3);
    pB[i] = B + (long)(bcol + rb) * 1024 + cb * 8;
    pdB[i] = 8192 + g * 8;
  }

  auto STAGE_I = [&](int t, int i) {              // one gload pair (1 A + 1 B)
    f16* base = lds + (t & 3) * 14336;
    const int off = t * 32;
    gload16(pA[i] + off, base + pdA[i]);
    gload16(pB[i] + off, base + pdB[i]);
  };

  const int aoff0 = fr * 4 + (kq ^ ((fr >> 1) & 3));
  f32x4 acc[8][3] = {};

  STAGE_I(0, 0); STAGE_I(0, 1);
  STAGE_I(1, 0); STAGE_I(1, 1);
  STAGE_I(2, 0); STAGE_I(2, 1);   // 12 loads in flight
  WAIT_VM_8;                      // tile 0 landed; tiles 1,2 in flight
  RAW_BARRIER;

#pragma unroll 1
  for (int t = 0; t < NT; ++t) {
    const f16* base = lds + (t & 3) * 14336;
    f16x8 av[4], bv[3];
    // ---------------- phase 0 ----------------
    if (t + 3 < NT) STAGE_I(t + 3, 0);
    SCHED_FENCE;
#pragma unroll
    for (int m = 0; m < 4; m++)
      av[m] = *(const f16x8*)(base + ((wr * 8 + m) * 64 + aoff0) * 8);
#pragma unroll
    for (int n = 0; n < 3; n++)
      bv[n] = *(const f16x8*)(base + 8192 + ((wc * 3 + n) * 64 + aoff0) * 8);
    RAW_BARRIER;
    WAIT_LGKM_0;
    __builtin_amdgcn_s_setprio(1);
#pragma unroll
    for (int m = 0; m < 4; m++)
#pragma unroll
      for (int n = 0; n < 3; n++)
        acc[m][n] = __builtin_amdgcn_mfma_f32_16x16x32_f16(av[m], bv[n], acc[m][n], 0, 0, 0);
    __builtin_amdgcn_s_setprio(0);
    RAW_BARRIER;
    // ---------------- phase 1 ----------------
    if (t + 3 < NT) STAGE_I(t + 3, 1);
    SCHED_FENCE;
#pragma unroll
    for (int m = 0; m < 4; m++)
      av[m] = *(const f16x8*)(base + ((wr * 8 + 4 + m) * 64 + aoff0) * 8);
    RAW_BARRIER;
    WAIT_LGKM_0;
    __builtin_amdgcn_s_setprio(1);
#pragma unroll
    for (int m = 0; m < 4; m++)
#pragma unroll
      for (int n = 0; n < 3; n++)
        acc[4 + m][n] = __builtin_amdgcn_mfma_f32_16x16x32_f16(av[m], bv[n], acc[4 + m][n], 0, 0, 0);
    __builtin_amdgcn_s_setprio(0);
    if (t + 1 < NT) {
      if (t + 3 < NT)      { WAIT_VM_8; }   // t+1 landed; t+2,t+3 in flight
      else if (t + 2 < NT) { WAIT_VM_4; }
      else                 { WAIT_VM_0; }
      RAW_BARRIER;
    }
  }

#pragma unroll
  for (int m = 0; m < 8; m++) {
    const int row0 = brow + wr * 128 + m * 16 + kq * 4;
    const int bI = row0 >> 11, srow = row0 & 2047;
#pragma unroll
    for (int n = 0; n < 3; n++) {
      const int col = bcol + wc * 48 + n * 16 + fr;
      const float bb = bias[col];
      const float v0 = acc[m][n][0] + bb, v1 = acc[m][n][1] + bb;
      const float v2 = acc[m][n][2] + bb, v3 = acc[m][n][3] + bb;
      f16x4 w = {(f16)v0, (f16)v1, (f16)v2, (f16)v3};
      *(f16x4*)&CT[((long)bI * 3072 + col) * 2048 + srow] = w;
      const int tcol = bcol + wc * 48 + n * 16;
      if (tcol < 2048) {
        float h0 = v0 * v0 + v1 * v1;
        float h1 = v2 * v2 + v3 * v3;
        h0 += __shfl_xor(h0, 1, 64);
        h1 += __shfl_xor(h1, 1, 64);
        if (!(lane & 1)) {
          const int tau = tcol >> 10;
          float* dst = (tau ? nk : nq)
                     + ((long)bI * 1024 + (srow >> 1)) * 512 + ((col & 1023) >> 1);
          dst[0]   = h0;
          dst[512] = h1;
        }
      }
    }
  }
}

// ============ 128x128 GEMM: R6 1-phase 4-buffer stage-lead-3 (REVERT: R8 2-phase neutral) ==
template<typename OutT, bool BIAS, bool TRANSC>
__device__ __forceinline__ void gemm_body(
    const f16* __restrict__ A, const f16* __restrict__ B,
    OutT* __restrict__ C, const float* __restrict__ bias,
    int K, int lda, int ldb, int ldc, float alpha, f16* lds, int brow, int bcol)
{
  const int NT = K >> 5;
  const int tid = threadIdx.x;
  const int lane = tid & 63;
  const int wid = tid >> 6;
  const int wr = (wid >> 1) << 6;
  const int wc = (wid & 1) << 6;
  const int fr = lane & 15;
  const int kq = lane >> 4;
  const int kqsw = kq ^ ((fr >> 1) & 3);

  const int srow = tid >> 2;
  const int skq  = (tid & 3) ^ ((tid >> 3) & 3);
  const f16* gA0 = A + (long)(brow + srow) * lda + skq * 8;
  const f16* gA1 = A + (long)(brow + 64 + srow) * lda + skq * 8;
  const f16* gB0 = B + (long)(bcol + srow) * ldb + skq * 8;
  const f16* gB1 = B + (long)(bcol + 64 + srow) * ldb + skq * 8;
  const int dA0 = tid * 8, dA1 = 2048 + tid * 8;
  const int dB0 = 4096 + tid * 8, dB1 = 6144 + tid * 8;

  auto STAGE = [&](int t) {
    f16* base = lds + (t & 3) * 8192;
    const int off = t * 32;
    gload16(gA0 + off, base + dA0);
    gload16(gA1 + off, base + dA1);
    gload16(gB0 + off, base + dB0);
    gload16(gB1 + off, base + dB1);
  };

  f32x4 acc[4][4] = {};

  STAGE(0); STAGE(1); STAGE(2);
  WAIT_VM_8;
  RAW_BARRIER;

#pragma unroll 1
  for (int t = 0; t < NT; ++t) {
    if (t + 3 < NT) STAGE(t + 3);
    SCHED_FENCE;
    const f16* base = lds + (t & 3) * 8192;
    f16x8 av[4], bv[4];
#pragma unroll
    for (int m = 0; m < 4; m++)
      av[m] = *(const f16x8*)(base + (wr + m * 16 + fr) * 32 + kqsw * 8);
#pragma unroll
    for (int n = 0; n < 4; n++)
      bv[n] = *(const f16x8*)(base + 4096 + (wc + n * 16 + fr) * 32 + kqsw * 8);
    __builtin_amdgcn_s_setprio(1);
#pragma unroll
    for (int m = 0; m < 4; m++)
#pragma unroll
      for (int n = 0; n < 4; n++)
        acc[m][n] = __builtin_amdgcn_mfma_f32_16x16x32_f16(av[m], bv[n], acc[m][n], 0, 0, 0);
    __builtin_amdgcn_s_setprio(0);
    if (t + 1 < NT) {
      WAIT_LGKM_0;
      if (t + 3 < NT)      { WAIT_VM_8; }
      else if (t + 2 < NT) { WAIT_VM_4; }
      else                 { WAIT_VM_0; }
      RAW_BARRIER;
    }
  }

#pragma unroll
  for (int m = 0; m < 4; m++)
#pragma unroll
    for (int n = 0; n < 4; n++) {
      const int row0 = brow + wr + m * 16 + kq * 4;
      const int col  = bcol + wc + n * 16 + fr;
      if constexpr (TRANSC) {
        f16x4 v;
#pragma unroll
        for (int i = 0; i < 4; i++) v[i] = (f16)(acc[m][n][i] * alpha);
        *(f16x4*)&C[(long)col * ldc + row0] = v;
      } else {
        float bb = 0.f;
        if constexpr (BIAS) bb = bias[col];
#pragma unroll
        for (int i = 0; i < 4; i++)
          C[(long)(row0 + i) * ldc + col] = (OutT)(acc[m][n][i] * alpha + bb);
      }
    }
}

template<typename OutT, bool BIAS, bool TRANSC>
__global__ __launch_bounds__(256)
void gemm_bt(const f16* __restrict__ A, const f16* __restrict__ B,
             OutT* __restrict__ C, const float* __restrict__ bias,
             int K, int lda, int ldb, int ldc,
             long sA, long sB, long sC, float alpha)
{
  __shared__ f16 lds[32768];
  const int bz = blockIdx.z;
  gemm_body<OutT, BIAS, TRANSC>(A + bz * sA, B + bz * sB, C + bz * sC, bias,
                                K, lda, ldb, ldc, alpha, lds,
                                blockIdx.y << 7, blockIdx.x << 7);
}

// merged stage-1: 3 products x 4 batches x 64 tiles of 128^2 = 768 blocks, XCD swizzle
__global__ __launch_bounds__(256)
void gemm3_128(const f16* __restrict__ PqTm, const f16* __restrict__ PkTm, f16* __restrict__ A1,
               const f16* __restrict__ qkvT, const f16* __restrict__ xT, f16* __restrict__ B2,
               const f16* __restrict__ WOT, f16* __restrict__ Zt, float alpha)
{
  __shared__ f16 lds[32768];
  const int s = blockIdx.x;
  const int tile = (s & 7) * 96 + (s >> 3);
  const int z = tile >> 6, rem = tile & 63;
  const int p = z >> 2, b = z & 3;
  const f16 *A, *B; f16* C;
  if (p == 0)      { A = PqTm + (long)b * 1024 * 2048; B = PkTm + (long)b * 1024 * 2048;
                     C = A1 + (long)b * 1024 * 1024; }
  else if (p == 1) { A = qkvT + (long)b * 3072 * 2048 + 2048L * 2048; B = xT + (long)b * 1024 * 2048;
                     C = B2 + (long)b * 1024 * 1024; }
  else             { A = xT + (long)b * 1024 * 2048; B = WOT + (long)b * 1024 * 2048;
                     C = Zt + (long)b * 1024 * 1024; }
  gemm_body<f16, false, false>(A, B, C, nullptr, 2048, 2048, 2048, 1024, alpha, lds,
                               (rem >> 3) << 7, (rem & 7) << 7);
}

// ---------------- f32 -> f16 convert (vectorized x4)
__global__ __launch_bounds__(256)
void cvt_f32_f16(const float* __restrict__ in, f16* __restrict__ out, long n4) {
  long i = (long)blockIdx.x * 256 + threadIdx.x;
  if (i >= n4) return;
  float4 v = ((const float4*)in)[i];
  f16x4 o = {(f16)v.x, (f16)v.y, (f16)v.z, (f16)v.w};
  ((f16x4*)out)[i] = o;
}

// ---------------- fused x: f32 -> (xh f16, xT f16 transposed) in one pass
__global__ __launch_bounds__(256)
void cvtT_x(const float* __restrict__ x, f16* __restrict__ xh, f16* __restrict__ xT) {
  __shared__ f16 t[32][33];
  const int b = blockIdx.z;
  const int s0 = blockIdx.x * 32, d0 = blockIdx.y * 32;
  const int tx = threadIdx.x, ty = threadIdx.y;  // (32,8)
#pragma unroll
  for (int j = 0; j < 32; j += 8) {
    const long idx = ((long)b * 2048 + s0 + ty + j) * 1024 + d0 + tx;
    f16 h = (f16)x[idx];
    xh[idx] = h;
    t[ty + j][tx] = h;
  }
  __syncthreads();
#pragma unroll
  for (int j = 0; j < 32; j += 8)
    xT[((long)b * 1024 + d0 + ty + j) * 2048 + s0 + tx] = t[tx][ty + j];
}

// ---------------- WO row norms^2 (exact f32)
__global__ __launch_bounds__(256)
void row_norms(const float* __restrict__ WO, float* __restrict__ wno) {
  const int wid = threadIdx.x >> 6, lane = threadIdx.x & 63;
  const long row = (long)blockIdx.x * 4 + wid;
  const float* p = WO + row * 1024;
  float s = 0.f;
#pragma unroll
  for (int j = 0; j < 4; j++) {
    float4 v = *(const float4*)(p + lane * 4 + j * 256);
    s += v.x*v.x + v.y*v.y + v.z*v.z + v.w*v.w;
  }
  for (int off = 32; off; off >>= 1) s += __shfl_down(s, off, 64);
  if (lane == 0) wno[row] = s;
}

// ---------------- norms transpose: [b][s2:1024][d2:512] -> [b][d2:512][s2:1024]
__global__ __launch_bounds__(256)
void normsT(const float* __restrict__ nq, const float* __restrict__ nk,
            float* __restrict__ nqT, float* __restrict__ nkT) {
  __shared__ float t[32][33];
  const int z = blockIdx.z;
  const float* src = (z < 4 ? nq : nk) + (long)(z & 3) * 524288;
  float* dst = (z < 4 ? nqT : nkT) + (long)(z & 3) * 524288;
  const int s0 = blockIdx.x * 32, d0 = blockIdx.y * 32;
  const int tx = threadIdx.x, ty = threadIdx.y;
#pragma unroll
  for (int j = 0; j < 32; j += 8)
    t[ty + j][tx] = src[(long)(s0 + ty + j) * 512 + d0 + tx];
  __syncthreads();
#pragma unroll
  for (int j = 0; j < 32; j += 8)
    dst[(long)(d0 + ty + j) * 1024 + s0 + tx] = t[tx][ty + j];
}

// ---------------- radix-select: 2 passes x 4096 bins (bits 31:20, 19:8)
__global__ __launch_bounds__(256)
void select_init(unsigned* hist, unsigned* prefix, unsigned* rankrem) {
  int i = blockIdx.x * 256 + threadIdx.x;
  if (i < 12 * 4096) hist[i] = 0;
  if (i < 12) { prefix[i] = 0; rankrem[i] = (i < 8) ? 262144u : 1024u; }
}

__global__ __launch_bounds__(256)
void hist_pass(const float* __restrict__ nq, const float* __restrict__ nk,
               const float* __restrict__ wno, unsigned* __restrict__ hist,
               const unsigned* __restrict__ prefix,
               int shift, int nbins, unsigned himask) {
  __shared__ unsigned lh[4096];
  const int pid = blockIdx.y;
  for (int i = threadIdx.x; i < nbins; i += 256) lh[i] = 0;
  __syncthreads();
  const float* base; long N;
  if (pid < 4)      { base = nq  + (long)pid       * 524288; N = 524288; }
  else if (pid < 8) { base = nk  + (long)(pid - 4) * 524288; N = 524288; }
  else              { base = wno + (long)(pid - 8) * 2048;   N = 2048;  }
  const unsigned pref = prefix[pid];
  long chunk = (N + gridDim.x - 1) / gridDim.x;
  long s = (long)blockIdx.x * chunk;
  long e = s + chunk; if (e > N) e = N;
  for (long i = s + threadIdx.x; i < e; i += 256) {
    unsigned u = __float_as_uint(base[i]);
    if ((u & himask) == pref) atomicAdd(&lh[(u >> shift) & (nbins - 1)], 1u);
  }
  __syncthreads();
  for (int i = threadIdx.x; i < nbins; i += 256)
    if (lh[i]) atomicAdd(&hist[pid * 4096 + i], lh[i]);
}

__global__ __launch_bounds__(256)
void scan_pass(unsigned* __restrict__ hist, unsigned* __restrict__ prefix,
               unsigned* __restrict__ rankrem, float* __restrict__ thr,
               int shift, int nbins, int final_pass) {
  __shared__ unsigned buf[2][256];
  const int pid = blockIdx.x;
  const int tid = threadIdx.x;
  unsigned* h = hist + pid * 4096;
  const int per = nbins >> 8;
  const unsigned r = rankrem[pid];
  const unsigned oldpref = prefix[pid];
  unsigned local[16];
  unsigned s = 0;
#pragma unroll
  for (int j = 0; j < 16; j++) {
    if (j < per) {
      local[j] = h[tid * per + j];
      h[tid * per + j] = 0;
      s += local[j];
    }
  }
  buf[0][tid] = s;
  __syncthreads();
  int src = 0;
#pragma unroll
  for (int d = 1; d < 256; d <<= 1) {
    unsigned v = buf[src][tid];
    if (tid >= d) v += buf[src][tid - d];
    buf[src ^ 1][tid] = v;
    __syncthreads();
    src ^= 1;
  }
  const unsigned incl = buf[src][tid];
  const unsigned excl = incl - s;
  if (excl <= r && r < incl) {
    unsigned accu = excl;
#pragma unroll
    for (int j = 0; j < 16; j++) {
      if (j < per) {
        if (accu + local[j] > r) {
          rankrem[pid] = r - accu;
          unsigned np = oldpref | ((unsigned)(tid * per + j) << shift);
          prefix[pid] = np;
          if (final_pass) thr[pid] = __uint_as_float(np);
          break;
        }
        accu += local[j];
      }
    }
  }
}

// ---------------- masked q/k copy, d-major, coalesced norm reads (transposed norms)
__global__ __launch_bounds__(256)
void mask_qkT(const f16* __restrict__ qkvT, const float* __restrict__ nqT,
              const float* __restrict__ nkT, const float* __restrict__ thr,
              f16* __restrict__ PqTm, f16* __restrict__ PkTm) {
  const int d  = blockIdx.x & 1023;
  const int tau = (blockIdx.x >> 10) & 1;
  const int bI = blockIdx.x >> 11;
  const int s8 = threadIdx.x;
  f16x8 v = *(const f16x8*)(qkvT + ((long)bI * 3072 + tau * 1024 + d) * 2048 + s8 * 8);
  const float t = thr[tau * 4 + bI];
  const float4 nv = *(const float4*)((tau ? nkT : nqT)
                     + ((long)bI * 512 + (d >> 1)) * 1024 + s8 * 4);
  if (nv.x < t) { v[0] = (f16)0.f; v[1] = (f16)0.f; }
  if (nv.y < t) { v[2] = (f16)0.f; v[3] = (f16)0.f; }
  if (nv.z < t) { v[4] = (f16)0.f; v[5] = (f16)0.f; }
  if (nv.w < t) { v[6] = (f16)0.f; v[7] = (f16)0.f; }
  f16* dst = (tau ? PkTm : PqTm) + ((long)bI * 1024 + d) * 2048 + s8 * 8;
  *(f16x8*)dst = v;
}

// ---------------- fused WO row-mask + transpose + f32->f16
__global__ __launch_bounds__(256)
void wo_maskT(const float* __restrict__ WO, const float* __restrict__ wno,
              const float* __restrict__ thr, f16* __restrict__ WOT) {
  __shared__ f16 t[32][33];
  const int b = blockIdx.z;
  const int s0 = blockIdx.x * 32, d0 = blockIdx.y * 32;
  const int tx = threadIdx.x, ty = threadIdx.y;
  const float tb = thr[8 + b];
#pragma unroll
  for (int j = 0; j < 32; j += 8) {
    const int s = s0 + ty + j;
    const float m = (wno[(long)b * 2048 + s] >= tb) ? 1.f : 0.f;
    t[ty + j][tx] = (f16)(WO[((long)b * 2048 + s) * 1024 + d0 + tx] * m);
  }
  __syncthreads();
#pragma unroll
  for (int j = 0; j < 32; j += 8)
    WOT[((long)b * 1024 + d0 + ty + j) * 2048 + s0 + tx] = t[tx][ty + j];
}

extern "C" void kernel_launch(void* const* d_in, const int* in_sizes, int n_in,
                              void* d_out, int out_size, void* d_ws, size_t ws_size,
                              hipStream_t stream) {
  const float* x    = (const float*)d_in[0];
  const float* Wqkv = (const float*)d_in[1];
  const float* bqkv = (const float*)d_in[2];
  const float* WO   = (const float*)d_in[3];
  float* out = (float*)d_out;

  char* w = (char*)d_ws;
  auto alloc = [&](size_t bytes) { char* p = w; w += (bytes + 255) & ~(size_t)255; return p; };
  f16*      xh      = (f16*)alloc(8192L * 1024 * 2);
  f16*      wh      = (f16*)alloc(3072L * 1024 * 2);
  f16*      xT      = (f16*)alloc(4L * 1024 * 2048 * 2);
  f16*      qkvT    = (f16*)alloc(4L * 3072 * 2048 * 2);
  float*    nq      = (float*)alloc(4L * 524288 * 4);
  float*    nk      = (float*)alloc(4L * 524288 * 4);
  float*    nqT     = (float*)alloc(4L * 524288 * 4);
  float*    nkT     = (float*)alloc(4L * 524288 * 4);
  float*    wno     = (float*)alloc(8192L * 4);
  unsigned* hist    = (unsigned*)alloc(12L * 4096 * 4);
  unsigned* prefix  = (unsigned*)alloc(256);
  unsigned* rankrem = (unsigned*)alloc(256);
  float*    thr     = (float*)alloc(256);
  f16*      WOT     = (f16*)alloc(4L * 1024 * 2048 * 2);
  f16*      PqTm    = (f16*)alloc(4L * 1024 * 2048 * 2);
  f16*      PkTm    = (f16*)alloc(4L * 1024 * 2048 * 2);
  f16*      Zt      = (f16*)alloc(4L * 1024 * 1024 * 2);
  f16*      A1      = (f16*)alloc(4L * 1024 * 1024 * 2);
  f16*      B2      = (f16*)alloc(4L * 1024 * 1024 * 2);
  f16*      M1      = (f16*)alloc(4L * 1024 * 1024 * 2);
  f16*      M2T     = (f16*)alloc(4L * 1024 * 1024 * 2);
  if ((size_t)(w - (char*)d_ws) > ws_size) return;

  // 1. conversions
  cvtT_x<<<dim3(64, 32, 4), dim3(32, 8), 0, stream>>>(x, xh, xT);
  cvt_f32_f16<<<3072, 256, 0, stream>>>(Wqkv, wh, 3072L * 1024 / 4);
  // 2. qkv GEMM (phase-split) -> qkvT + fused f32-acc tile-norms
  gemm256_qkv<<<512, 512, 0, stream>>>(xh, wh, qkvT, bqkv, nq, nk);
  // 3. WO row norms + norms transpose
  row_norms<<<2048, 256, 0, stream>>>(WO, wno);
  normsT<<<dim3(32, 16, 8), dim3(32, 8), 0, stream>>>(nq, nk, nqT, nkT);
  // 4. medians via 2-pass radix select
  select_init<<<192, 256, 0, stream>>>(hist, prefix, rankrem);
  hist_pass<<<dim3(32, 12), 256, 0, stream>>>(nq, nk, wno, hist, prefix, 20, 4096, 0u);
  scan_pass<<<12, 256, 0, stream>>>(hist, prefix, rankrem, thr, 20, 4096, 0);
  hist_pass<<<dim3(32, 12), 256, 0, stream>>>(nq, nk, wno, hist, prefix, 8, 4096, 0xFFF00000u);
  scan_pass<<<12, 256, 0, stream>>>(hist, prefix, rankrem, thr, 8, 4096, 1);
  // 5. masks
  mask_qkT<<<8192, 256, 0, stream>>>(qkvT, nqT, nkT, thr, PqTm, PkTm);
  wo_maskT<<<dim3(64, 32, 4), dim3(32, 8), 0, stream>>>(WO, wno, thr, WOT);
  // 6. chain: out = x.[Pq^T.Pk].[x^T.v].[WO_^T.x]/32
  gemm3_128<<<768, 256, 0, stream>>>(PqTm, PkTm, A1, qkvT, xT, B2, WOT, Zt, 0.03125f);
  gemm_bt<f16, false, false><<<dim3(8, 8, 4), 256, 0, stream>>>(
      A1, B2, M1, nullptr, 1024, 1024, 1024, 1024,
      1024L * 1024, 1024L * 1024, 1024L * 1024, 1.f);
  gemm_bt<f16, false, true><<<dim3(8, 8, 4), 256, 0, stream>>>(
      M1, Zt, M2T, nullptr, 1024, 1024, 1024, 1024,
      1024L * 1024, 1024L * 1024, 1024L * 1024, 0.25f);
  gemm_bt<float, false, false><<<dim3(8, 16, 4), 256, 0, stream>>>(
      xh, M2T, out, nullptr, 1024, 1024, 1024, 1024,
      2048L * 1024, 1024L * 1024, 2048L * 1024, 4096.f);
}

// Round 10
// 325.980 us; speedup vs baseline: 1.0649x; 1.0003x over previous
//
#include <hip/hip_runtime.h>

typedef _Float16 f16;
typedef _Float16 f16x8 __attribute__((ext_vector_type(8)));
typedef _Float16 f16x4 __attribute__((ext_vector_type(4)));
typedef float f32x4 __attribute__((ext_vector_type(4)));

__device__ __forceinline__ void gload16(const void* g, void* l) {
  __builtin_amdgcn_global_load_lds(
      (const __attribute__((address_space(1))) void*)g,
      (__attribute__((address_space(3))) void*)l, 16, 0, 0);
}

#define SCHED_FENCE __builtin_amdgcn_sched_barrier(0)
#define RAW_BARRIER do { SCHED_FENCE; __builtin_amdgcn_s_barrier(); SCHED_FENCE; } while (0)
#define WAIT_VM_0    do { asm volatile("s_waitcnt vmcnt(0)"     ::: "memory"); SCHED_FENCE; } while (0)
#define WAIT_VM_4    do { asm volatile("s_waitcnt vmcnt(4)"     ::: "memory"); SCHED_FENCE; } while (0)
#define WAIT_VM_8    do { asm volatile("s_waitcnt vmcnt(8)"     ::: "memory"); SCHED_FENCE; } while (0)
#define WAIT_LGKM_0  do { asm volatile("s_waitcnt lgkmcnt(0)"   ::: "memory"); SCHED_FENCE; } while (0)
#define WAIT_LGKM_12 do { asm volatile("s_waitcnt lgkmcnt(12)"  ::: "memory"); SCHED_FENCE; } while (0)

// ============ qkv GEMM: REVERT to R6 BN=256 4-buf body (best measured, 73.2us) ============
// + grafted fused epilogue: C^T write (qkvT) + f32-acc 2x2 tile-norms (R7-proven).
// Grid 384 1D, XCD-chunked swizzle. 512 thr = 8 waves (2Mx4N), per-wave 128x64 = 8x4 frags.
__global__ __launch_bounds__(512, 2)
void gemm256_qkv(const f16* __restrict__ A, const f16* __restrict__ B,
                 f16* __restrict__ CT, const float* __restrict__ bias,
                 float* __restrict__ nq, float* __restrict__ nk)
{
  __shared__ f16 lds[65536];
  const int s = blockIdx.x;                       // 384 blocks
  const int tile = (s & 7) * 48 + (s >> 3);       // XCD swizzle (384%8==0)
  const int brow = (tile / 12) << 8;
  const int bcol = (tile % 12) << 8;
  const int NT = 32;
  const int tid = threadIdx.x;
  const int lane = tid & 63;
  const int wid = tid >> 6;
  const int wr = wid >> 2;
  const int wc = wid & 3;
  const int fr = lane & 15;
  const int kq = lane >> 4;

  const f16* pA[2]; const f16* pB[2]; int pdst[2];
#pragma unroll
  for (int i = 0; i < 2; i++) {
    const int p = wid * 128 + i * 64 + lane;
    const int rr = ((p >> 6) << 4) | ((p >> 2) & 15);
    const int c4 = (p & 3) ^ ((p >> 3) & 3);
    pA[i] = A + (long)(brow + rr) * 1024 + c4 * 8;
    pB[i] = B + (long)(bcol + rr) * 1024 + c4 * 8;
    pdst[i] = p * 8;
  }

  auto STAGE = [&](int t) {
    f16* base = lds + (t & 3) * 16384;
    const int off = t * 32;
#pragma unroll
    for (int i = 0; i < 2; i++) {
      gload16(pA[i] + off, base + pdst[i]);
      gload16(pB[i] + off, base + 8192 + pdst[i]);
    }
  };

  const int aoff0 = fr * 4 + (kq ^ ((fr >> 1) & 3));
  f32x4 acc[8][4] = {};
  f16x8 avA[8], bvA[4], avB[8], bvB[4];

  STAGE(0); STAGE(1); STAGE(2);
  WAIT_VM_4;
  RAW_BARRIER;
#pragma unroll
  for (int m = 0; m < 8; m++)
    avA[m] = *(const f16x8*)(lds + ((wr * 8 + m) * 64 + aoff0) * 8);
#pragma unroll
  for (int n = 0; n < 4; n++)
    bvA[n] = *(const f16x8*)(lds + 8192 + ((wc * 4 + n) * 64 + aoff0) * 8);

#define GEMM_ITER(T, AVC, BVC, AVN, BVN)                                        \
  do {                                                                          \
    if ((T) + 3 < NT) STAGE((T) + 3);                                           \
    if ((T) + 1 < NT) {                                                         \
      const f16* nb_ = lds + (((T) + 1) & 3) * 16384;                           \
      _Pragma("unroll")                                                         \
      for (int m = 0; m < 8; m++)                                               \
        AVN[m] = *(const f16x8*)(nb_ + ((wr * 8 + m) * 64 + aoff0) * 8);        \
      _Pragma("unroll")                                                         \
      for (int n = 0; n < 4; n++)                                               \
        BVN[n] = *(const f16x8*)(nb_ + 8192 + ((wc * 4 + n) * 64 + aoff0) * 8); \
      WAIT_LGKM_12;                                                             \
    } else {                                                                    \
      WAIT_LGKM_0;                                                              \
    }                                                                           \
    __builtin_amdgcn_s_setprio(1);                                              \
    _Pragma("unroll")                                                           \
    for (int m = 0; m < 8; m++)                                                 \
      _Pragma("unroll")                                                         \
      for (int n = 0; n < 4; n++)                                               \
        acc[m][n] = __builtin_amdgcn_mfma_f32_16x16x32_f16(AVC[m], BVC[n],      \
                                                           acc[m][n], 0, 0, 0); \
    __builtin_amdgcn_s_setprio(0);                                              \
    if ((T) + 3 < NT)      { WAIT_VM_4; }                                       \
    else if ((T) + 2 < NT) { WAIT_VM_0; }                                       \
    RAW_BARRIER;                                                                \
  } while (0)

#pragma unroll 1
  for (int t = 0; t < NT; t += 2) {
    GEMM_ITER(t,     avA, bvA, avB, bvB);
    GEMM_ITER(t + 1, avB, bvB, avA, bvA);
  }
#undef GEMM_ITER

#pragma unroll
  for (int m = 0; m < 8; m++) {
    const int row0 = brow + wr * 128 + m * 16 + kq * 4;
    const int bI = row0 >> 11, srow = row0 & 2047;
#pragma unroll
    for (int n = 0; n < 4; n++) {
      const int col = bcol + wc * 64 + n * 16 + fr;
      const float bb = bias[col];
      const float v0 = acc[m][n][0] + bb, v1 = acc[m][n][1] + bb;
      const float v2 = acc[m][n][2] + bb, v3 = acc[m][n][3] + bb;
      f16x4 w = {(f16)v0, (f16)v1, (f16)v2, (f16)v3};
      *(f16x4*)&CT[((long)bI * 3072 + col) * 2048 + srow] = w;
      const int tcol = bcol + wc * 64 + n * 16;
      if (tcol < 2048) {
        float h0 = v0 * v0 + v1 * v1;
        float h1 = v2 * v2 + v3 * v3;
        h0 += __shfl_xor(h0, 1, 64);
        h1 += __shfl_xor(h1, 1, 64);
        if (!(lane & 1)) {
          const int tau = tcol >> 10;
          float* dst = (tau ? nk : nq)
                     + ((long)bI * 1024 + (srow >> 1)) * 512 + ((col & 1023) >> 1);
          dst[0]   = h0;
          dst[512] = h1;
        }
      }
    }
  }
}

// ============ 128x128 GEMM body A: m97-style, 16KB LDS, 2 barriers/K-tile =================
// High-occupancy variant (~5-6 blocks/CU co-resident): m114's verified overlap mechanism.
// For grids >= 512 (gemm3: 768 -> 3/CU; s4: 512 -> 2/CU).
template<typename OutT, bool BIAS, bool TRANSC>
__device__ __forceinline__ void gemm_body_hi(
    const f16* __restrict__ A, const f16* __restrict__ B,
    OutT* __restrict__ C, const float* __restrict__ bias,
    int K, int lda, int ldb, int ldc, float alpha,
    f16* lA, f16* lB, int brow, int bcol)
{
  const int tid = threadIdx.x;
  const int lane = tid & 63;
  const int wid = tid >> 6;
  const int wr = (wid >> 1) << 6;
  const int wc = (wid & 1) << 6;
  const int fr = lane & 15;
  const int kq = lane >> 4;
  const int kqsw = kq ^ ((fr >> 1) & 3);

  const int srow = tid >> 2;
  const int skq  = (tid & 3) ^ ((tid >> 3) & 3);
  const f16* gA0 = A + (long)(brow + srow) * lda + skq * 8;
  const f16* gA1 = A + (long)(brow + 64 + srow) * lda + skq * 8;
  const f16* gB0 = B + (long)(bcol + srow) * ldb + skq * 8;
  const f16* gB1 = B + (long)(bcol + 64 + srow) * ldb + skq * 8;
  f16* lAd0 = &lA[tid * 8];
  f16* lAd1 = &lA[2048 + tid * 8];
  f16* lBd0 = &lB[tid * 8];
  f16* lBd1 = &lB[2048 + tid * 8];

  f32x4 acc[4][4] = {};

  for (int t = 0; t < K; t += 32) {
    gload16(gA0 + t, lAd0);
    gload16(gA1 + t, lAd1);
    gload16(gB0 + t, lBd0);
    gload16(gB1 + t, lBd1);
    __syncthreads();
    f16x8 av[4], bv[4];
#pragma unroll
    for (int m = 0; m < 4; m++)
      av[m] = *(const f16x8*)&lA[(wr + m * 16 + fr) * 32 + kqsw * 8];
#pragma unroll
    for (int n = 0; n < 4; n++)
      bv[n] = *(const f16x8*)&lB[(wc + n * 16 + fr) * 32 + kqsw * 8];
#pragma unroll
    for (int m = 0; m < 4; m++)
#pragma unroll
      for (int n = 0; n < 4; n++)
        acc[m][n] = __builtin_amdgcn_mfma_f32_16x16x32_f16(av[m], bv[n], acc[m][n], 0, 0, 0);
    __syncthreads();
  }

#pragma unroll
  for (int m = 0; m < 4; m++)
#pragma unroll
    for (int n = 0; n < 4; n++) {
      const int row0 = brow + wr + m * 16 + kq * 4;
      const int col  = bcol + wc + n * 16 + fr;
      if constexpr (TRANSC) {
        f16x4 v;
#pragma unroll
        for (int i = 0; i < 4; i++) v[i] = (f16)(acc[m][n][i] * alpha);
        *(f16x4*)&C[(long)col * ldc + row0] = v;
      } else {
        float bb = 0.f;
        if constexpr (BIAS) bb = bias[col];
#pragma unroll
        for (int i = 0; i < 4; i++)
          C[(long)(row0 + i) * ldc + col] = (OutT)(acc[m][n][i] * alpha + bb);
      }
    }
}

// ============ 128x128 GEMM body B: 4-buf deep pipeline (R6-verified) ======================
// For structurally 1-block/CU grids (s2/s3: 256 blocks) where occupancy cannot help.
template<typename OutT, bool BIAS, bool TRANSC>
__device__ __forceinline__ void gemm_body_pipe(
    const f16* __restrict__ A, const f16* __restrict__ B,
    OutT* __restrict__ C, const float* __restrict__ bias,
    int K, int lda, int ldb, int ldc, float alpha, f16* lds, int brow, int bcol)
{
  const int NT = K >> 5;
  const int tid = threadIdx.x;
  const int lane = tid & 63;
  const int wid = tid >> 6;
  const int wr = (wid >> 1) << 6;
  const int wc = (wid & 1) << 6;
  const int fr = lane & 15;
  const int kq = lane >> 4;
  const int kqsw = kq ^ ((fr >> 1) & 3);

  const int srow = tid >> 2;
  const int skq  = (tid & 3) ^ ((tid >> 3) & 3);
  const f16* gA0 = A + (long)(brow + srow) * lda + skq * 8;
  const f16* gA1 = A + (long)(brow + 64 + srow) * lda + skq * 8;
  const f16* gB0 = B + (long)(bcol + srow) * ldb + skq * 8;
  const f16* gB1 = B + (long)(bcol + 64 + srow) * ldb + skq * 8;
  const int dA0 = tid * 8, dA1 = 2048 + tid * 8;
  const int dB0 = 4096 + tid * 8, dB1 = 6144 + tid * 8;

  auto STAGE = [&](int t) {
    f16* base = lds + (t & 3) * 8192;
    const int off = t * 32;
    gload16(gA0 + off, base + dA0);
    gload16(gA1 + off, base + dA1);
    gload16(gB0 + off, base + dB0);
    gload16(gB1 + off, base + dB1);
  };

  f32x4 acc[4][4] = {};

  STAGE(0); STAGE(1); STAGE(2);
  WAIT_VM_8;
  RAW_BARRIER;

#pragma unroll 1
  for (int t = 0; t < NT; ++t) {
    if (t + 3 < NT) STAGE(t + 3);
    SCHED_FENCE;
    const f16* base = lds + (t & 3) * 8192;
    f16x8 av[4], bv[4];
#pragma unroll
    for (int m = 0; m < 4; m++)
      av[m] = *(const f16x8*)(base + (wr + m * 16 + fr) * 32 + kqsw * 8);
#pragma unroll
    for (int n = 0; n < 4; n++)
      bv[n] = *(const f16x8*)(base + 4096 + (wc + n * 16 + fr) * 32 + kqsw * 8);
    __builtin_amdgcn_s_setprio(1);
#pragma unroll
    for (int m = 0; m < 4; m++)
#pragma unroll
      for (int n = 0; n < 4; n++)
        acc[m][n] = __builtin_amdgcn_mfma_f32_16x16x32_f16(av[m], bv[n], acc[m][n], 0, 0, 0);
    __builtin_amdgcn_s_setprio(0);
    if (t + 1 < NT) {
      WAIT_LGKM_0;
      if (t + 3 < NT)      { WAIT_VM_8; }
      else if (t + 2 < NT) { WAIT_VM_4; }
      else                 { WAIT_VM_0; }
      RAW_BARRIER;
    }
  }

#pragma unroll
  for (int m = 0; m < 4; m++)
#pragma unroll
    for (int n = 0; n < 4; n++) {
      const int row0 = brow + wr + m * 16 + kq * 4;
      const int col  = bcol + wc + n * 16 + fr;
      if constexpr (TRANSC) {
        f16x4 v;
#pragma unroll
        for (int i = 0; i < 4; i++) v[i] = (f16)(acc[m][n][i] * alpha);
        *(f16x4*)&C[(long)col * ldc + row0] = v;
      } else {
        float bb = 0.f;
        if constexpr (BIAS) bb = bias[col];
#pragma unroll
        for (int i = 0; i < 4; i++)
          C[(long)(row0 + i) * ldc + col] = (OutT)(acc[m][n][i] * alpha + bb);
      }
    }
}

// wrappers
template<typename OutT, bool BIAS, bool TRANSC>
__global__ __launch_bounds__(256)
void gemm_bt_pipe(const f16* __restrict__ A, const f16* __restrict__ B,
                  OutT* __restrict__ C, const float* __restrict__ bias,
                  int K, int lda, int ldb, int ldc,
                  long sA, long sB, long sC, float alpha)
{
  __shared__ f16 lds[32768];
  const int bz = blockIdx.z;
  gemm_body_pipe<OutT, BIAS, TRANSC>(A + bz * sA, B + bz * sB, C + bz * sC, bias,
                                     K, lda, ldb, ldc, alpha, lds,
                                     blockIdx.y << 7, blockIdx.x << 7);
}

template<typename OutT, bool BIAS, bool TRANSC>
__global__ __launch_bounds__(256)
void gemm_bt_hi(const f16* __restrict__ A, const f16* __restrict__ B,
                OutT* __restrict__ C, const float* __restrict__ bias,
                int K, int lda, int ldb, int ldc,
                long sA, long sB, long sC, float alpha)
{
  __shared__ f16 lA[4096];
  __shared__ f16 lB[4096];
  const int bz = blockIdx.z;
  gemm_body_hi<OutT, BIAS, TRANSC>(A + bz * sA, B + bz * sB, C + bz * sC, bias,
                                   K, lda, ldb, ldc, alpha, lA, lB,
                                   blockIdx.y << 7, blockIdx.x << 7);
}

// merged stage-1 on the HIGH-OCCUPANCY body: 768 blocks -> 3+ blocks/CU co-resident
__global__ __launch_bounds__(256)
void gemm3_128(const f16* __restrict__ PqTm, const f16* __restrict__ PkTm, f16* __restrict__ A1,
               const f16* __restrict__ qkvT, const f16* __restrict__ xT, f16* __restrict__ B2,
               const f16* __restrict__ WOT, f16* __restrict__ Zt, float alpha)
{
  __shared__ f16 lA[4096];
  __shared__ f16 lB[4096];
  const int s = blockIdx.x;
  const int tile = (s & 7) * 96 + (s >> 3);
  const int z = tile >> 6, rem = tile & 63;
  const int p = z >> 2, b = z & 3;
  const f16 *A, *B; f16* C;
  if (p == 0)      { A = PqTm + (long)b * 1024 * 2048; B = PkTm + (long)b * 1024 * 2048;
                     C = A1 + (long)b * 1024 * 1024; }
  else if (p == 1) { A = qkvT + (long)b * 3072 * 2048 + 2048L * 2048; B = xT + (long)b * 1024 * 2048;
                     C = B2 + (long)b * 1024 * 1024; }
  else             { A = xT + (long)b * 1024 * 2048; B = WOT + (long)b * 1024 * 2048;
                     C = Zt + (long)b * 1024 * 1024; }
  gemm_body_hi<f16, false, false>(A, B, C, nullptr, 2048, 2048, 2048, 1024, alpha, lA, lB,
                                  (rem >> 3) << 7, (rem & 7) << 7);
}

// ---------------- cvt combo: z<8192 -> x f32->(xh,xT); else Wqkv f32->f16
__global__ __launch_bounds__(256)
void cvt_combo(const float* __restrict__ x, f16* __restrict__ xh, f16* __restrict__ xT,
               const float* __restrict__ Wqkv, f16* __restrict__ wh) {
  const int z = blockIdx.x;
  const int tid = threadIdx.x;
  if (z < 8192) {
    __shared__ f16 t[32][33];
    const int b = z >> 11, r = z & 2047;
    const int s0 = (r & 63) * 32, d0 = (r >> 6) * 32;
    const int tx = tid & 31, ty = tid >> 5;
#pragma unroll
    for (int j = 0; j < 32; j += 8) {
      const long idx = ((long)b * 2048 + s0 + ty + j) * 1024 + d0 + tx;
      f16 h = (f16)x[idx];
      xh[idx] = h;
      t[ty + j][tx] = h;
    }
    __syncthreads();
#pragma unroll
    for (int j = 0; j < 32; j += 8)
      xT[((long)b * 1024 + d0 + ty + j) * 2048 + s0 + tx] = t[tx][ty + j];
  } else {
    const long i = (long)(z - 8192) * 256 + tid;
    float4 v = ((const float4*)Wqkv)[i];
    f16x4 o = {(f16)v.x, (f16)v.y, (f16)v.z, (f16)v.w};
    ((f16x4*)wh)[i] = o;
  }
}

// ---------------- norms combo: z<4096 normsT; z<6144 WO row-norms; else select_init
__global__ __launch_bounds__(256)
void norms_combo(const float* __restrict__ nq, const float* __restrict__ nk,
                 float* __restrict__ nqT, float* __restrict__ nkT,
                 const float* __restrict__ WO, float* __restrict__ wno,
                 unsigned* __restrict__ hist, unsigned* __restrict__ prefix,
                 unsigned* __restrict__ rankrem) {
  const int z = blockIdx.x;
  const int tid = threadIdx.x;
  if (z < 4096) {
    __shared__ float t[32][33];
    const int bz = z >> 9, r = z & 511;
    const int s0 = (r & 31) * 32, d0 = (r >> 5) * 32;
    const int tx = tid & 31, ty = tid >> 5;
    const float* src = (bz < 4 ? nq : nk) + (long)(bz & 3) * 524288;
    float* dst = (bz < 4 ? nqT : nkT) + (long)(bz & 3) * 524288;
#pragma unroll
    for (int j = 0; j < 32; j += 8)
      t[ty + j][tx] = src[(long)(s0 + ty + j) * 512 + d0 + tx];
    __syncthreads();
#pragma unroll
    for (int j = 0; j < 32; j += 8)
      dst[(long)(d0 + ty + j) * 1024 + s0 + tx] = t[tx][ty + j];
  } else if (z < 6144) {
    const int wid = tid >> 6, lane = tid & 63;
    const long row = (long)(z - 4096) * 4 + wid;
    const float* p = WO + row * 1024;
    float s = 0.f;
#pragma unroll
    for (int j = 0; j < 4; j++) {
      float4 v = *(const float4*)(p + lane * 4 + j * 256);
      s += v.x*v.x + v.y*v.y + v.z*v.z + v.w*v.w;
    }
    for (int off = 32; off; off >>= 1) s += __shfl_down(s, off, 64);
    if (lane == 0) wno[row] = s;
  } else {
    const int i = (z - 6144) * 256 + tid;
    if (i < 12 * 4096) hist[i] = 0;
    if (i < 12) { prefix[i] = 0; rankrem[i] = (i < 8) ? 262144u : 1024u; }
  }
}

// ---------------- radix-select: 2 passes x 4096 bins (bits 31:20, 19:8)
__global__ __launch_bounds__(256)
void hist_pass(const float* __restrict__ nq, const float* __restrict__ nk,
               const float* __restrict__ wno, unsigned* __restrict__ hist,
               const unsigned* __restrict__ prefix,
               int shift, int nbins, unsigned himask) {
  __shared__ unsigned lh[4096];
  const int pid = blockIdx.y;
  for (int i = threadIdx.x; i < nbins; i += 256) lh[i] = 0;
  __syncthreads();
  const float* base; long N;
  if (pid < 4)      { base = nq  + (long)pid       * 524288; N = 524288; }
  else if (pid < 8) { base = nk  + (long)(pid - 4) * 524288; N = 524288; }
  else              { base = wno + (long)(pid - 8) * 2048;   N = 2048;  }
  const unsigned pref = prefix[pid];
  long chunk = (N + gridDim.x - 1) / gridDim.x;
  long s = (long)blockIdx.x * chunk;
  long e = s + chunk; if (e > N) e = N;
  for (long i = s + threadIdx.x; i < e; i += 256) {
    unsigned u = __float_as_uint(base[i]);
    if ((u & himask) == pref) atomicAdd(&lh[(u >> shift) & (nbins - 1)], 1u);
  }
  __syncthreads();
  for (int i = threadIdx.x; i < nbins; i += 256)
    if (lh[i]) atomicAdd(&hist[pid * 4096 + i], lh[i]);
}

__global__ __launch_bounds__(256)
void scan_pass(unsigned* __restrict__ hist, unsigned* __restrict__ prefix,
               unsigned* __restrict__ rankrem, float* __restrict__ thr,
               int shift, int nbins, int final_pass) {
  __shared__ unsigned buf[2][256];
  const int pid = blockIdx.x;
  const int tid = threadIdx.x;
  unsigned* h = hist + pid * 4096;
  const int per = nbins >> 8;
  const unsigned r = rankrem[pid];
  const unsigned oldpref = prefix[pid];
  unsigned local[16];
  unsigned s = 0;
#pragma unroll
  for (int j = 0; j < 16; j++) {
    if (j < per) {
      local[j] = h[tid * per + j];
      h[tid * per + j] = 0;
      s += local[j];
    }
  }
  buf[0][tid] = s;
  __syncthreads();
  int src = 0;
#pragma unroll
  for (int d = 1; d < 256; d <<= 1) {
    unsigned v = buf[src][tid];
    if (tid >= d) v += buf[src][tid - d];
    buf[src ^ 1][tid] = v;
    __syncthreads();
    src ^= 1;
  }
  const unsigned incl = buf[src][tid];
  const unsigned excl = incl - s;
  if (excl <= r && r < incl) {
    unsigned accu = excl;
#pragma unroll
    for (int j = 0; j < 16; j++) {
      if (j < per) {
        if (accu + local[j] > r) {
          rankrem[pid] = r - accu;
          unsigned np = oldpref | ((unsigned)(tid * per + j) << shift);
          prefix[pid] = np;
          if (final_pass) thr[pid] = __uint_as_float(np);
          break;
        }
        accu += local[j];
      }
    }
  }
}

// ---------------- mask combo: z<8192 masked q/k copy; else WO mask+transpose
__global__ __launch_bounds__(256)
void mask_combo(const f16* __restrict__ qkvT, const float* __restrict__ nqT,
                const float* __restrict__ nkT, const float* __restrict__ thr,
                f16* __restrict__ PqTm, f16* __restrict__ PkTm,
                const float* __restrict__ WO, const float* __restrict__ wno,
                f16* __restrict__ WOT) {
  const int z = blockIdx.x;
  const int tid = threadIdx.x;
  if (z < 8192) {
    const int d  = z & 1023;
    const int tau = (z >> 10) & 1;
    const int bI = z >> 11;
    f16x8 v = *(const f16x8*)(qkvT + ((long)bI * 3072 + tau * 1024 + d) * 2048 + tid * 8);
    const float t = thr[tau * 4 + bI];
    const float4 nv = *(const float4*)((tau ? nkT : nqT)
                       + ((long)bI * 512 + (d >> 1)) * 1024 + tid * 4);
    if (nv.x < t) { v[0] = (f16)0.f; v[1] = (f16)0.f; }
    if (nv.y < t) { v[2] = (f16)0.f; v[3] = (f16)0.f; }
    if (nv.z < t) { v[4] = (f16)0.f; v[5] = (f16)0.f; }
    if (nv.w < t) { v[6] = (f16)0.f; v[7] = (f16)0.f; }
    f16* dst = (tau ? PkTm : PqTm) + ((long)bI * 1024 + d) * 2048 + tid * 8;
    *(f16x8*)dst = v;
  } else {
    __shared__ f16 t[32][33];
    const int zz = z - 8192;
    const int b = zz >> 11, r = zz & 2047;
    const int s0 = (r & 63) * 32, d0 = (r >> 6) * 32;
    const int tx = tid & 31, ty = tid >> 5;
    const float tb = thr[8 + b];
#pragma unroll
    for (int j = 0; j < 32; j += 8) {
      const int s = s0 + ty + j;
      const float m = (wno[(long)b * 2048 + s] >= tb) ? 1.f : 0.f;
      t[ty + j][tx] = (f16)(WO[((long)b * 2048 + s) * 1024 + d0 + tx] * m);
    }
    __syncthreads();
#pragma unroll
    for (int j = 0; j < 32; j += 8)
      WOT[((long)b * 1024 + d0 + ty + j) * 2048 + s0 + tx] = t[tx][ty + j];
  }
}

extern "C" void kernel_launch(void* const* d_in, const int* in_sizes, int n_in,
                              void* d_out, int out_size, void* d_ws, size_t ws_size,
                              hipStream_t stream) {
  const float* x    = (const float*)d_in[0];
  const float* Wqkv = (const float*)d_in[1];
  const float* bqkv = (const float*)d_in[2];
  const float* WO   = (const float*)d_in[3];
  float* out = (float*)d_out;

  char* w = (char*)d_ws;
  auto alloc = [&](size_t bytes) { char* p = w; w += (bytes + 255) & ~(size_t)255; return p; };
  f16*      xh      = (f16*)alloc(8192L * 1024 * 2);
  f16*      wh      = (f16*)alloc(3072L * 1024 * 2);
  f16*      xT      = (f16*)alloc(4L * 1024 * 2048 * 2);
  f16*      qkvT    = (f16*)alloc(4L * 3072 * 2048 * 2);
  float*    nq      = (float*)alloc(4L * 524288 * 4);
  float*    nk      = (float*)alloc(4L * 524288 * 4);
  float*    nqT     = (float*)alloc(4L * 524288 * 4);
  float*    nkT     = (float*)alloc(4L * 524288 * 4);
  float*    wno     = (float*)alloc(8192L * 4);
  unsigned* hist    = (unsigned*)alloc(12L * 4096 * 4);
  unsigned* prefix  = (unsigned*)alloc(256);
  unsigned* rankrem = (unsigned*)alloc(256);
  float*    thr     = (float*)alloc(256);
  f16*      WOT     = (f16*)alloc(4L * 1024 * 2048 * 2);
  f16*      PqTm    = (f16*)alloc(4L * 1024 * 2048 * 2);
  f16*      PkTm    = (f16*)alloc(4L * 1024 * 2048 * 2);
  f16*      Zt      = (f16*)alloc(4L * 1024 * 1024 * 2);
  f16*      A1      = (f16*)alloc(4L * 1024 * 1024 * 2);
  f16*      B2      = (f16*)alloc(4L * 1024 * 1024 * 2);
  f16*      M1      = (f16*)alloc(4L * 1024 * 1024 * 2);
  f16*      M2T     = (f16*)alloc(4L * 1024 * 1024 * 2);
  if ((size_t)(w - (char*)d_ws) > ws_size) return;

  // 1. conversions (merged)
  cvt_combo<<<11264, 256, 0, stream>>>(x, xh, xT, Wqkv, wh);
  // 2. qkv GEMM (R6-best body) -> qkvT + fused f32-acc tile-norms
  gemm256_qkv<<<384, 512, 0, stream>>>(xh, wh, qkvT, bqkv, nq, nk);
  // 3. normsT + WO row-norms + select-init (merged)
  norms_combo<<<6336, 256, 0, stream>>>(nq, nk, nqT, nkT, WO, wno, hist, prefix, rankrem);
  // 4. medians via 2-pass radix select
  hist_pass<<<dim3(32, 12), 256, 0, stream>>>(nq, nk, wno, hist, prefix, 20, 4096, 0u);
  scan_pass<<<12, 256, 0, stream>>>(hist, prefix, rankrem, thr, 20, 4096, 0);
  hist_pass<<<dim3(32, 12), 256, 0, stream>>>(nq, nk, wno, hist, prefix, 8, 4096, 0xFFF00000u);
  scan_pass<<<12, 256, 0, stream>>>(hist, prefix, rankrem, thr, 8, 4096, 1);
  // 5. masks (merged)
  mask_combo<<<16384, 256, 0, stream>>>(qkvT, nqT, nkT, thr, PqTm, PkTm, WO, wno, WOT);
  // 6. chain: out = x.[Pq^T.Pk].[x^T.v].[WO_^T.x]/32
  gemm3_128<<<768, 256, 0, stream>>>(PqTm, PkTm, A1, qkvT, xT, B2, WOT, Zt, 0.03125f);
  gemm_bt_pipe<f16, false, false><<<dim3(8, 8, 4), 256, 0, stream>>>(
      A1, B2, M1, nullptr, 1024, 1024, 1024, 1024,
      1024L * 1024, 1024L * 1024, 1024L * 1024, 1.f);
  gemm_bt_pipe<f16, false, true><<<dim3(8, 8, 4), 256, 0, stream>>>(
      M1, Zt, M2T, nullptr, 1024, 1024, 1024, 1024,
      1024L * 1024, 1024L * 1024, 1024L * 1024, 0.25f);
  gemm_bt_hi<float, false, false><<<dim3(8, 16, 4), 256, 0, stream>>>(
      xh, M2T, out, nullptr, 1024, 1024, 1024, 1024,
      2048L * 1024, 1024L * 1024, 2048L * 1024, 4096.f);
}